// Round 1
// baseline (771.291 us; speedup 1.0000x reference)
//
#include <hip/hip_runtime.h>

constexpr int Bc = 4, Hc = 8, Nc = 2048, Dc = 64, Fc = 128, Mc = 4;
constexpr int BHc = Bc*Hc;        // 32
constexpr int T2c = 2*Nc;         // 4096
constexpr int Jc  = Mc*Fc;        // 512
constexpr float DNORM = 0.4204482076268573f;   // 32^-0.25

// workspace offsets (in floats)
constexpr size_t OFF_AS    = 0;
constexpr size_t OFF_XSG   = OFF_AS    + (size_t)BHc*T2c*Fc;   // 16777216
constexpr size_t OFF_DIAG1 = OFF_XSG   + (size_t)BHc*Jc*Dc;    // +1048576
constexpr size_t OFF_DIAG2 = OFF_DIAG1 + (size_t)BHc*T2c;      // +131072
constexpr size_t OFF_STASN = OFF_DIAG2 + (size_t)BHc*Jc;       // +16384
constexpr size_t OFF_VBUF  = OFF_STASN + (size_t)BHc*Fc*Fc;    // +524288
constexpr size_t OFF_DINV  = OFF_VBUF  + (size_t)BHc*Fc*Fc;    // +524288
constexpr size_t OFF_GMAX  = OFF_DINV  + (size_t)BHc*Fc;       // +4096
constexpr size_t OFF_CTX   = OFF_GMAX  + 64;
// total = OFF_CTX + 262144 floats  ~= 77.2 MB

// ---------------- diag1: 0.5*|x_t|^2 for all rows of X = [q;k]*scale ----------------
__global__ __launch_bounds__(256) void diag1_kernel(
    const float* __restrict__ q, const float* __restrict__ k,
    const float* __restrict__ mask, float* __restrict__ diag1) {
  int gid = blockIdx.x*256 + threadIdx.x;     // over BH*T2*16
  int kq  = gid & 15;
  int row = gid >> 4;                         // bh*T2 + t
  int t   = row & (T2c - 1);
  int bh  = row >> 12;
  int b   = bh >> 3;
  int tn  = (t < Nc) ? t : t - Nc;
  const float* src = ((t < Nc) ? q : k) + ((size_t)bh*Nc + tn)*Dc;
  float sc = DNORM * mask[b*Nc + tn];
  float4 x = *(const float4*)(src + kq*4);
  float s = x.x*x.x + x.y*x.y + x.z*x.z + x.w*x.w;
  s += __shfl_xor(s, 1);
  s += __shfl_xor(s, 2);
  s += __shfl_xor(s, 4);
  s += __shfl_xor(s, 8);
  if (kq == 0) diag1[row] = 0.5f * sc * sc * s;
}

// ---------------- gather sketch rows: XSg[bh][j][:] = X[bh][S[b,j]][:], diag2 = diag1 gather --------
__global__ __launch_bounds__(256) void gather_kernel(
    const float* __restrict__ q, const float* __restrict__ k,
    const float* __restrict__ mask, const int* __restrict__ sketch,
    const float* __restrict__ diag1,
    float* __restrict__ xsg, float* __restrict__ diag2) {
  int gid = blockIdx.x*256 + threadIdx.x;     // over BH*J*16
  int kq  = gid & 15;
  int idx = gid >> 4;                         // bh*J + j
  int j   = idx & (Jc - 1);
  int bh  = idx >> 9;
  int b   = bh >> 3;
  int t   = sketch[b*Jc + j];
  int tn  = (t < Nc) ? t : t - Nc;
  const float* src = ((t < Nc) ? q : k) + ((size_t)bh*Nc + tn)*Dc;
  float sc = DNORM * mask[b*Nc + tn];
  float4 x = *(const float4*)(src + kq*4);
  x.x *= sc; x.y *= sc; x.z *= sc; x.w *= sc;
  *(float4*)(xsg + (size_t)idx*Dc + kq*4) = x;
  if (kq == 0) diag2[idx] = diag1[bh*T2c + t];
}

// ---------------- AS GEMM: AS[t,f] = sum_m sign[m,f]*exp(x_t . xs[m,f] - d1 - d2) ----------------
__global__ __launch_bounds__(256) void as_gemm_kernel(
    const float* __restrict__ q, const float* __restrict__ k,
    const float* __restrict__ mask, const float* __restrict__ xsg,
    const float* __restrict__ diag1, const float* __restrict__ diag2,
    const float* __restrict__ sign, float* __restrict__ AS) {
  __shared__ __align__(16) float Xa[32][68];
  __shared__ __align__(16) float XbT[64][132];
  __shared__ float d1s[32], d2s[128], sgs[128];
  int bh = blockIdx.y;
  int b  = bh >> 3;
  int row0 = blockIdx.x * 32;
  int tid = threadIdx.x;
  int tr = tid >> 5, tc = tid & 31;

  for (int i = tid; i < 32*16; i += 256) {
    int r = i >> 4, kq = i & 15;
    int t = row0 + r;
    int tn = (t < Nc) ? t : t - Nc;
    const float* src = ((t < Nc) ? q : k) + ((size_t)bh*Nc + tn)*Dc;
    float sc = DNORM * mask[b*Nc + tn];
    float4 x = *(const float4*)(src + kq*4);
    Xa[r][kq*4+0] = x.x*sc; Xa[r][kq*4+1] = x.y*sc;
    Xa[r][kq*4+2] = x.z*sc; Xa[r][kq*4+3] = x.w*sc;
  }
  if (tid < 32) d1s[tid] = diag1[bh*T2c + row0 + tid];

  float out_acc[4][4] = {};
  for (int m = 0; m < Mc; ++m) {
    __syncthreads();
    for (int i = tid; i < 128*16; i += 256) {
      int c = i >> 4, kq = i & 15;
      float4 x = *(const float4*)(xsg + ((size_t)bh*Jc + m*Fc + c)*Dc + kq*4);
      XbT[kq*4+0][c] = x.x; XbT[kq*4+1][c] = x.y;
      XbT[kq*4+2][c] = x.z; XbT[kq*4+3][c] = x.w;
    }
    if (tid < 128) {
      d2s[tid] = diag2[bh*Jc + m*Fc + tid];
      sgs[tid] = sign[(b*Mc + m)*Fc + tid];
    }
    __syncthreads();
    float acc[4][4] = {};
    #pragma unroll 4
    for (int kk = 0; kk < Dc; ++kk) {
      float a0 = Xa[tr*4+0][kk];
      float a1 = Xa[tr*4+1][kk];
      float a2 = Xa[tr*4+2][kk];
      float a3 = Xa[tr*4+3][kk];
      float4 bv = *(const float4*)&XbT[kk][tc*4];
      acc[0][0] += a0*bv.x; acc[0][1] += a0*bv.y; acc[0][2] += a0*bv.z; acc[0][3] += a0*bv.w;
      acc[1][0] += a1*bv.x; acc[1][1] += a1*bv.y; acc[1][2] += a1*bv.z; acc[1][3] += a1*bv.w;
      acc[2][0] += a2*bv.x; acc[2][1] += a2*bv.y; acc[2][2] += a2*bv.z; acc[2][3] += a2*bv.w;
      acc[3][0] += a3*bv.x; acc[3][1] += a3*bv.y; acc[3][2] += a3*bv.z; acc[3][3] += a3*bv.w;
    }
    #pragma unroll
    for (int i = 0; i < 4; ++i) {
      float d1v = d1s[tr*4+i];
      #pragma unroll
      for (int jj = 0; jj < 4; ++jj) {
        int c = tc*4 + jj;
        out_acc[i][jj] += sgs[c] * __expf(acc[i][jj] - d1v - d2s[c]);
      }
    }
  }
  #pragma unroll
  for (int i = 0; i < 4; ++i) {
    float4 o;
    o.x = out_acc[i][0]; o.y = out_acc[i][1]; o.z = out_acc[i][2]; o.w = out_acc[i][3];
    *(float4*)(AS + ((size_t)bh*T2c + row0 + tr*4 + i)*Fc + tc*4) = o;
  }
}

// ---------------- STAS build + normalize + global colsum max ----------------
__global__ __launch_bounds__(256) void stas_kernel(
    const float* __restrict__ AS, const int* __restrict__ sketch,
    const float* __restrict__ sign,
    float* __restrict__ STASn, float* __restrict__ Dinv,
    unsigned int* __restrict__ gmax) {
  extern __shared__ float stas[];   // [128][129] padded
  __shared__ int   Ssh[Jc];
  __shared__ float sgn[Jc];
  __shared__ float Dl[Fc];
  __shared__ float red[Fc];
  int bh = blockIdx.x;
  int b  = bh >> 3;
  int tid = threadIdx.x;
  for (int i = tid; i < Jc; i += 256) {
    Ssh[i] = sketch[b*Jc + i];
    sgn[i] = sign[b*Jc + i];
  }
  __syncthreads();
  for (int i = tid; i < Fc*Fc; i += 256) {
    int dd = i >> 7, e = i & 127;
    float vsum = 0.f;
    #pragma unroll
    for (int m = 0; m < Mc; ++m) {
      int t = Ssh[m*Fc + dd];
      vsum += sgn[m*Fc + dd] * AS[((size_t)bh*T2c + t)*Fc + e];
    }
    if (dd == e) vsum += 0.1f;
    stas[dd*129 + e] = vsum;
  }
  __syncthreads();
  if (tid < Fc) {                       // row sums -> D_inv
    float s = 0.f;
    for (int e = 0; e < Fc; ++e) s += stas[tid*129 + e];
    float di = 1.0f / sqrtf(s);
    Dl[tid] = di;
    Dinv[bh*Fc + tid] = di;
  }
  __syncthreads();
  for (int i = tid; i < Fc*Fc; i += 256) {  // normalize, write out
    int dd = i >> 7, e = i & 127;
    float vv = stas[dd*129 + e] * Dl[dd] * Dl[e];
    stas[dd*129 + e] = vv;
    STASn[(size_t)bh*Fc*Fc + i] = vv;
  }
  __syncthreads();
  if (tid < Fc) {                       // column sums of STASn
    float s = 0.f;
    for (int dd = 0; dd < Fc; ++dd) s += stas[dd*129 + tid];
    red[tid] = s;
  }
  __syncthreads();
  if (tid == 0) {
    float mx = 0.f;
    for (int e = 0; e < Fc; ++e) mx = fmaxf(mx, red[e]);
    atomicMax(gmax, __float_as_uint(mx));   // positive floats: uint order == float order
  }
}

// ---------------- Newton-Schulz order-4 inverse, 6 iters, one block per head ----------------
__device__ __forceinline__ void mm128(const float* __restrict__ A, const float* __restrict__ Bm,
                                      float o[8][4], int tr, int tc) {
  #pragma unroll
  for (int i = 0; i < 8; ++i) { o[i][0]=0.f; o[i][1]=0.f; o[i][2]=0.f; o[i][3]=0.f; }
  #pragma unroll 2
  for (int kk = 0; kk < Fc; ++kk) {
    float4 bv = *(const float4*)(Bm + kk*Fc + tc*4);
    #pragma unroll
    for (int i = 0; i < 8; ++i) {
      float a = A[(tr*8+i)*Fc + kk];
      o[i][0] += a*bv.x; o[i][1] += a*bv.y; o[i][2] += a*bv.z; o[i][3] += a*bv.w;
    }
  }
}

__global__ __launch_bounds__(512) void newton_kernel(
    const float* __restrict__ STASn, const float* __restrict__ gmaxf,
    float* __restrict__ Vout) {
  extern __shared__ float sm[];
  float* Va = sm;             // V slot
  float* Zb = sm + Fc*Fc;     // K / Z slot
  int bh = blockIdx.x;
  int tid = threadIdx.x;
  int tr = tid >> 5, tc = tid & 31;   // 16 x 32 thread grid, 8x4 tile
  const float* Kp = STASn + (size_t)bh*Fc*Fc;
  float ginv = 1.0f / gmaxf[0];

  for (int i = tid; i < Fc*Fc; i += 512) {   // V0 = K^T * ginv
    int dd = i >> 7, e = i & 127;
    Va[i] = Kp[e*Fc + dd] * ginv;
  }
  __syncthreads();
  float vs_[8][4];
  #pragma unroll
  for (int i = 0; i < 8; ++i) {
    float4 t4 = *(const float4*)&Va[(tr*8+i)*Fc + tc*4];
    vs_[i][0]=t4.x; vs_[i][1]=t4.y; vs_[i][2]=t4.z; vs_[i][3]=t4.w;
  }

  float w[8][4], fin[8][4];
  for (int it = 0; it < 6; ++it) {
    __syncthreads();
    for (int i = tid; i < Fc*Fc/4; i += 512)     // stage K
      ((float4*)Zb)[i] = ((const float4*)Kp)[i];
    __syncthreads();
    mm128(Zb, Va, w, tr, tc);                    // Z = K @ V
    __syncthreads();
    #pragma unroll
    for (int i = 0; i < 8; ++i) {
      float4 t4; t4.x=w[i][0]; t4.y=w[i][1]; t4.z=w[i][2]; t4.w=w[i][3];
      *(float4*)&Zb[(tr*8+i)*Fc + tc*4] = t4;
    }
    __syncthreads();
    mm128(Va, Zb, w, tr, tc);                    // W1 = V @ Z
    #pragma unroll
    for (int i = 0; i < 8; ++i)
      #pragma unroll
      for (int jj = 0; jj < 4; ++jj)
        fin[i][jj] = 13.f*vs_[i][jj] - 15.f*w[i][jj];
    __syncthreads();
    #pragma unroll
    for (int i = 0; i < 8; ++i) {
      float4 t4; t4.x=w[i][0]; t4.y=w[i][1]; t4.z=w[i][2]; t4.w=w[i][3];
      *(float4*)&Va[(tr*8+i)*Fc + tc*4] = t4;
    }
    __syncthreads();
    mm128(Va, Zb, w, tr, tc);                    // W2 = W1 @ Z
    #pragma unroll
    for (int i = 0; i < 8; ++i)
      #pragma unroll
      for (int jj = 0; jj < 4; ++jj)
        fin[i][jj] += 7.f*w[i][jj];
    __syncthreads();
    #pragma unroll
    for (int i = 0; i < 8; ++i) {
      float4 t4; t4.x=w[i][0]; t4.y=w[i][1]; t4.z=w[i][2]; t4.w=w[i][3];
      *(float4*)&Va[(tr*8+i)*Fc + tc*4] = t4;
    }
    __syncthreads();
    mm128(Va, Zb, w, tr, tc);                    // W3 = W2 @ Z
    #pragma unroll
    for (int i = 0; i < 8; ++i)
      #pragma unroll
      for (int jj = 0; jj < 4; ++jj) {
        fin[i][jj] = 0.25f*(fin[i][jj] - w[i][jj]);
        vs_[i][jj] = fin[i][jj];
      }
    __syncthreads();
    #pragma unroll
    for (int i = 0; i < 8; ++i) {
      float4 t4; t4.x=fin[i][0]; t4.y=fin[i][1]; t4.z=fin[i][2]; t4.w=fin[i][3];
      *(float4*)&Va[(tr*8+i)*Fc + tc*4] = t4;
    }
  }
  __syncthreads();
  for (int i = tid; i < Fc*Fc/4; i += 512)
    ((float4*)(Vout + (size_t)bh*Fc*Fc))[i] = ((const float4*)Va)[i];
}

// ---------------- K-normalize in place: ASk <- (ASk*Dinv) @ STASinv * Dinv * mask ----------------
__global__ __launch_bounds__(256) void kn_kernel(
    float* __restrict__ AS, const float* __restrict__ Vinv,
    const float* __restrict__ Dinv, const float* __restrict__ mask) {
  extern __shared__ float sm[];
  float* Bs  = sm;            // [128][128]  Dinv[e]*STASinv[e][f]
  float* Asl = sm + Fc*Fc;    // [32][132]
  __shared__ float Dl[Fc];
  int bh = blockIdx.y;
  int b  = bh >> 3;
  int row0 = blockIdx.x * 32;
  int tid = threadIdx.x;
  int tr = tid >> 5, tc = tid & 31;
  if (tid < Fc) Dl[tid] = Dinv[bh*Fc + tid];
  __syncthreads();
  const float4* V4 = (const float4*)(Vinv + (size_t)bh*Fc*Fc);
  for (int i = tid; i < Fc*Fc/4; i += 256) {
    int e = i >> 5;
    float4 x = V4[i];
    float d = Dl[e];
    x.x*=d; x.y*=d; x.z*=d; x.w*=d;
    ((float4*)Bs)[i] = x;
  }
  for (int i = tid; i < 32*32; i += 256) {
    int r = i >> 5, kq = i & 31;
    float4 x = *(const float4*)(AS + ((size_t)bh*T2c + Nc + row0 + r)*Fc + kq*4);
    *(float4*)&Asl[r*132 + kq*4] = x;
  }
  __syncthreads();
  float acc[4][4] = {};
  #pragma unroll 2
  for (int e = 0; e < Fc; ++e) {
    float4 bv = *(const float4*)(Bs + e*Fc + tc*4);
    float a0 = Asl[(tr*4+0)*132 + e];
    float a1 = Asl[(tr*4+1)*132 + e];
    float a2 = Asl[(tr*4+2)*132 + e];
    float a3 = Asl[(tr*4+3)*132 + e];
    acc[0][0] += a0*bv.x; acc[0][1] += a0*bv.y; acc[0][2] += a0*bv.z; acc[0][3] += a0*bv.w;
    acc[1][0] += a1*bv.x; acc[1][1] += a1*bv.y; acc[1][2] += a1*bv.z; acc[1][3] += a1*bv.w;
    acc[2][0] += a2*bv.x; acc[2][1] += a2*bv.y; acc[2][2] += a2*bv.z; acc[2][3] += a2*bv.w;
    acc[3][0] += a3*bv.x; acc[3][1] += a3*bv.y; acc[3][2] += a3*bv.z; acc[3][3] += a3*bv.w;
  }
  #pragma unroll
  for (int i = 0; i < 4; ++i) {
    int row = row0 + tr*4 + i;
    float mk = mask[b*Nc + row];
    float4 o;
    o.x = acc[i][0]*Dl[tc*4+0]*mk;
    o.y = acc[i][1]*Dl[tc*4+1]*mk;
    o.z = acc[i][2]*Dl[tc*4+2]*mk;
    o.w = acc[i][3]*Dl[tc*4+3]*mk;
    *(float4*)(AS + ((size_t)bh*T2c + Nc + row)*Fc + tc*4) = o;
  }
}

// ---------------- context[f][e] = sum_t KN[t][f] * v[t][e] (split-K + atomics) ----------------
__global__ __launch_bounds__(256) void ctx_kernel(
    const float* __restrict__ AS, const float* __restrict__ v,
    const float* __restrict__ mask, float* __restrict__ ctx) {
  __shared__ __align__(16) float KNs[32][132];
  __shared__ __align__(16) float vsl[32][68];
  int bh = blockIdx.y;
  int b  = bh >> 3;
  int t0 = blockIdx.x * 128;
  int tid = threadIdx.x;
  int tf = tid >> 3, te = tid & 7;
  float acc[4][8] = {};
  for (int sub = 0; sub < 4; ++sub) {
    __syncthreads();
    for (int i = tid; i < 32*32; i += 256) {
      int r = i >> 5, kq = i & 31;
      *(float4*)&KNs[r][kq*4] =
          *(const float4*)(AS + ((size_t)bh*T2c + Nc + t0 + sub*32 + r)*Fc + kq*4);
    }
    for (int i = tid; i < 32*16; i += 256) {
      int r = i >> 4, kq = i & 15;
      int t = t0 + sub*32 + r;
      float4 x = *(const float4*)(v + ((size_t)bh*Nc + t)*Dc + kq*4);
      float mk = mask[b*Nc + t];
      x.x*=mk; x.y*=mk; x.z*=mk; x.w*=mk;
      *(float4*)&vsl[r][kq*4] = x;
    }
    __syncthreads();
    #pragma unroll 2
    for (int tl = 0; tl < 32; ++tl) {
      float4 av = *(const float4*)&KNs[tl][tf*4];
      float4 b0 = *(const float4*)&vsl[tl][te*8];
      float4 b1 = *(const float4*)&vsl[tl][te*8+4];
      float a[4]  = {av.x, av.y, av.z, av.w};
      float bb[8] = {b0.x,b0.y,b0.z,b0.w,b1.x,b1.y,b1.z,b1.w};
      #pragma unroll
      for (int i = 0; i < 4; ++i)
        #pragma unroll
        for (int jj = 0; jj < 8; ++jj)
          acc[i][jj] += a[i]*bb[jj];
    }
  }
  #pragma unroll
  for (int i = 0; i < 4; ++i)
    #pragma unroll
    for (int jj = 0; jj < 8; ++jj)
      atomicAdd(ctx + (size_t)bh*Fc*Dc + (tf*4+i)*Dc + te*8 + jj, acc[i][jj]);
}

// ---------------- out = Q @ context ----------------
__global__ __launch_bounds__(256) void out_kernel(
    const float* __restrict__ AS, const float* __restrict__ ctx,
    float* __restrict__ out) {
  extern __shared__ float sm[];
  float* Asq = sm;             // [64][132]
  float* Cs  = sm + 64*132;    // [128][64]
  int bh = blockIdx.y;
  int row0 = blockIdx.x * 64;
  int tid = threadIdx.x;
  int tr = tid >> 4, tc = tid & 15;
  for (int i = tid; i < 64*32; i += 256) {
    int r = i >> 5, kq = i & 31;
    *(float4*)&Asq[r*132 + kq*4] =
        *(const float4*)(AS + ((size_t)bh*T2c + row0 + r)*Fc + kq*4);
  }
  for (int i = tid; i < 128*16; i += 256) {
    int r = i >> 4, kq = i & 15;
    *(float4*)&Cs[r*64 + kq*4] =
        *(const float4*)(ctx + (size_t)bh*Fc*Dc + r*Dc + kq*4);
  }
  __syncthreads();
  float acc[4][4] = {};
  #pragma unroll 2
  for (int kk = 0; kk < Fc; ++kk) {
    float4 bv = *(const float4*)&Cs[kk*64 + tc*4];
    float a0 = Asq[(tr*4+0)*132 + kk];
    float a1 = Asq[(tr*4+1)*132 + kk];
    float a2 = Asq[(tr*4+2)*132 + kk];
    float a3 = Asq[(tr*4+3)*132 + kk];
    acc[0][0] += a0*bv.x; acc[0][1] += a0*bv.y; acc[0][2] += a0*bv.z; acc[0][3] += a0*bv.w;
    acc[1][0] += a1*bv.x; acc[1][1] += a1*bv.y; acc[1][2] += a1*bv.z; acc[1][3] += a1*bv.w;
    acc[2][0] += a2*bv.x; acc[2][1] += a2*bv.y; acc[2][2] += a2*bv.z; acc[2][3] += a2*bv.w;
    acc[3][0] += a3*bv.x; acc[3][1] += a3*bv.y; acc[3][2] += a3*bv.z; acc[3][3] += a3*bv.w;
  }
  #pragma unroll
  for (int i = 0; i < 4; ++i) {
    float4 o;
    o.x = acc[i][0]; o.y = acc[i][1]; o.z = acc[i][2]; o.w = acc[i][3];
    *(float4*)(out + ((size_t)bh*Nc + row0 + tr*4 + i)*Dc + tc*4) = o;
  }
}

extern "C" void kernel_launch(void* const* d_in, const int* in_sizes, int n_in,
                              void* d_out, int out_size, void* d_ws, size_t ws_size,
                              hipStream_t stream) {
  const float* q    = (const float*)d_in[0];
  const float* k    = (const float*)d_in[1];
  const float* v    = (const float*)d_in[2];
  const float* mask = (const float*)d_in[3];
  const float* sign = (const float*)d_in[4];
  const int*   sketch = (const int*)d_in[5];
  float* out = (float*)d_out;
  float* ws  = (float*)d_ws;

  hipMemsetAsync(ws + OFF_GMAX, 0, sizeof(float), stream);
  hipMemsetAsync(ws + OFF_CTX, 0, (size_t)BHc*Fc*Dc*sizeof(float), stream);

  diag1_kernel<<<BHc*T2c*16/256, 256, 0, stream>>>(q, k, mask, ws + OFF_DIAG1);
  gather_kernel<<<BHc*Jc*16/256, 256, 0, stream>>>(q, k, mask, sketch, ws + OFF_DIAG1,
                                                   ws + OFF_XSG, ws + OFF_DIAG2);
  as_gemm_kernel<<<dim3(T2c/32, BHc), 256, 0, stream>>>(q, k, mask, ws + OFF_XSG,
      ws + OFF_DIAG1, ws + OFF_DIAG2, sign, ws + OFF_AS);
  stas_kernel<<<BHc, 256, 128*129*sizeof(float), stream>>>(ws + OFF_AS, sketch, sign,
      ws + OFF_STASN, ws + OFF_DINV, (unsigned int*)(ws + OFF_GMAX));
  newton_kernel<<<BHc, 512, 2*Fc*Fc*sizeof(float), stream>>>(ws + OFF_STASN,
      ws + OFF_GMAX, ws + OFF_VBUF);
  kn_kernel<<<dim3(Nc/32, BHc), 256, (Fc*Fc + 32*132)*sizeof(float), stream>>>(
      ws + OFF_AS, ws + OFF_VBUF, ws + OFF_DINV, mask);
  ctx_kernel<<<dim3(Nc/128, BHc), 256, 0, stream>>>(ws + OFF_AS, v, mask, ws + OFF_CTX);
  out_kernel<<<dim3(Nc/64, BHc), 256, (64*132 + 128*64)*sizeof(float), stream>>>(
      ws + OFF_AS, ws + OFF_CTX, out);
}

// Round 3
// 685.489 us; speedup vs baseline: 1.1252x; 1.1252x over previous
//
#include <hip/hip_runtime.h>

constexpr int Bc = 4, Hc = 8, Nc = 2048, Dc = 64, Fc = 128, Mc = 4;
constexpr int BHc = Bc*Hc;        // 32
constexpr int T2c = 2*Nc;         // 4096
constexpr int Jc  = Mc*Fc;        // 512
constexpr float DNORM = 0.4204482076268573f;   // 32^-0.25

// workspace offsets (in floats)
constexpr size_t OFF_AS    = 0;
constexpr size_t OFF_XSG   = OFF_AS    + (size_t)BHc*T2c*Fc;   // 16777216
constexpr size_t OFF_DIAG1 = OFF_XSG   + (size_t)BHc*Jc*Dc;    // +1048576
constexpr size_t OFF_DIAG2 = OFF_DIAG1 + (size_t)BHc*T2c;      // +131072
constexpr size_t OFF_STASN = OFF_DIAG2 + (size_t)BHc*Jc;       // +16384
constexpr size_t OFF_VBUF  = OFF_STASN + (size_t)BHc*Fc*Fc;    // +524288
constexpr size_t OFF_DINV  = OFF_VBUF  + (size_t)BHc*Fc*Fc;    // +524288
constexpr size_t OFF_GMAX  = OFF_DINV  + (size_t)BHc*Fc;       // +4096
constexpr size_t OFF_CTX   = OFF_GMAX  + 64;

typedef __attribute__((ext_vector_type(8))) short bf16x8;
typedef __attribute__((ext_vector_type(4))) float f32x4;

__device__ __forceinline__ unsigned short f2bf_rne(float x) {
  unsigned int u = __float_as_uint(x);
  u += 0x7fff + ((u >> 16) & 1);
  return (unsigned short)(u >> 16);
}
__device__ __forceinline__ float bf2f(unsigned short h) {
  return __uint_as_float(((unsigned int)h) << 16);
}

// ---------------- diag1: 0.5*|x_t|^2 for all rows of X = [q;k]*scale ----------------
__global__ __launch_bounds__(256) void diag1_kernel(
    const float* __restrict__ q, const float* __restrict__ k,
    const float* __restrict__ mask, float* __restrict__ diag1) {
  int gid = blockIdx.x*256 + threadIdx.x;     // over BH*T2*16
  int kq  = gid & 15;
  int row = gid >> 4;                         // bh*T2 + t
  int t   = row & (T2c - 1);
  int bh  = row >> 12;
  int b   = bh >> 3;
  int tn  = (t < Nc) ? t : t - Nc;
  const float* src = ((t < Nc) ? q : k) + ((size_t)bh*Nc + tn)*Dc;
  float sc = DNORM * mask[b*Nc + tn];
  float4 x = *(const float4*)(src + kq*4);
  float s = x.x*x.x + x.y*x.y + x.z*x.z + x.w*x.w;
  s += __shfl_xor(s, 1);
  s += __shfl_xor(s, 2);
  s += __shfl_xor(s, 4);
  s += __shfl_xor(s, 8);
  if (kq == 0) diag1[row] = 0.5f * sc * sc * s;
}

// ---------------- gather sketch rows ----------------
__global__ __launch_bounds__(256) void gather_kernel(
    const float* __restrict__ q, const float* __restrict__ k,
    const float* __restrict__ mask, const int* __restrict__ sketch,
    const float* __restrict__ diag1,
    float* __restrict__ xsg, float* __restrict__ diag2) {
  int gid = blockIdx.x*256 + threadIdx.x;     // over BH*J*16
  int kq  = gid & 15;
  int idx = gid >> 4;                         // bh*J + j
  int j   = idx & (Jc - 1);
  int bh  = idx >> 9;
  int b   = bh >> 3;
  int t   = sketch[b*Jc + j];
  int tn  = (t < Nc) ? t : t - Nc;
  const float* src = ((t < Nc) ? q : k) + ((size_t)bh*Nc + tn)*Dc;
  float sc = DNORM * mask[b*Nc + tn];
  float4 x = *(const float4*)(src + kq*4);
  x.x *= sc; x.y *= sc; x.z *= sc; x.w *= sc;
  *(float4*)(xsg + (size_t)idx*Dc + kq*4) = x;
  if (kq == 0) diag2[idx] = diag1[bh*T2c + t];
}

// ---------------- AS GEMM ----------------
__global__ __launch_bounds__(256) void as_gemm_kernel(
    const float* __restrict__ q, const float* __restrict__ k,
    const float* __restrict__ mask, const float* __restrict__ xsg,
    const float* __restrict__ diag1, const float* __restrict__ diag2,
    const float* __restrict__ sign, float* __restrict__ AS) {
  __shared__ __align__(16) float Xa[32][68];
  __shared__ __align__(16) float XbT[64][132];
  __shared__ float d1s[32], d2s[128], sgs[128];
  int bh = blockIdx.y;
  int b  = bh >> 3;
  int row0 = blockIdx.x * 32;
  int tid = threadIdx.x;
  int tr = tid >> 5, tc = tid & 31;

  for (int i = tid; i < 32*16; i += 256) {
    int r = i >> 4, kq = i & 15;
    int t = row0 + r;
    int tn = (t < Nc) ? t : t - Nc;
    const float* src = ((t < Nc) ? q : k) + ((size_t)bh*Nc + tn)*Dc;
    float sc = DNORM * mask[b*Nc + tn];
    float4 x = *(const float4*)(src + kq*4);
    Xa[r][kq*4+0] = x.x*sc; Xa[r][kq*4+1] = x.y*sc;
    Xa[r][kq*4+2] = x.z*sc; Xa[r][kq*4+3] = x.w*sc;
  }
  if (tid < 32) d1s[tid] = diag1[bh*T2c + row0 + tid];

  float out_acc[4][4] = {};
  for (int m = 0; m < Mc; ++m) {
    __syncthreads();
    for (int i = tid; i < 128*16; i += 256) {
      int c = i >> 4, kq = i & 15;
      float4 x = *(const float4*)(xsg + ((size_t)bh*Jc + m*Fc + c)*Dc + kq*4);
      XbT[kq*4+0][c] = x.x; XbT[kq*4+1][c] = x.y;
      XbT[kq*4+2][c] = x.z; XbT[kq*4+3][c] = x.w;
    }
    if (tid < 128) {
      d2s[tid] = diag2[bh*Jc + m*Fc + tid];
      sgs[tid] = sign[(b*Mc + m)*Fc + tid];
    }
    __syncthreads();
    float acc[4][4] = {};
    #pragma unroll 4
    for (int kk = 0; kk < Dc; ++kk) {
      float a0 = Xa[tr*4+0][kk];
      float a1 = Xa[tr*4+1][kk];
      float a2 = Xa[tr*4+2][kk];
      float a3 = Xa[tr*4+3][kk];
      float4 bv = *(const float4*)&XbT[kk][tc*4];
      acc[0][0] += a0*bv.x; acc[0][1] += a0*bv.y; acc[0][2] += a0*bv.z; acc[0][3] += a0*bv.w;
      acc[1][0] += a1*bv.x; acc[1][1] += a1*bv.y; acc[1][2] += a1*bv.z; acc[1][3] += a1*bv.w;
      acc[2][0] += a2*bv.x; acc[2][1] += a2*bv.y; acc[2][2] += a2*bv.z; acc[2][3] += a2*bv.w;
      acc[3][0] += a3*bv.x; acc[3][1] += a3*bv.y; acc[3][2] += a3*bv.z; acc[3][3] += a3*bv.w;
    }
    #pragma unroll
    for (int i = 0; i < 4; ++i) {
      float d1v = d1s[tr*4+i];
      #pragma unroll
      for (int jj = 0; jj < 4; ++jj) {
        int c = tc*4 + jj;
        out_acc[i][jj] += sgs[c] * __expf(acc[i][jj] - d1v - d2s[c]);
      }
    }
  }
  #pragma unroll
  for (int i = 0; i < 4; ++i) {
    float4 o;
    o.x = out_acc[i][0]; o.y = out_acc[i][1]; o.z = out_acc[i][2]; o.w = out_acc[i][3];
    *(float4*)(AS + ((size_t)bh*T2c + row0 + tr*4 + i)*Fc + tc*4) = o;
  }
}

// ---------------- STAS build + normalize + global colsum max ----------------
__global__ __launch_bounds__(256) void stas_kernel(
    const float* __restrict__ AS, const int* __restrict__ sketch,
    const float* __restrict__ sign,
    float* __restrict__ STASn, float* __restrict__ Dinv,
    unsigned int* __restrict__ gmax) {
  extern __shared__ float stas[];   // [128][129] padded
  __shared__ int   Ssh[Jc];
  __shared__ float sgn[Jc];
  __shared__ float Dl[Fc];
  __shared__ float red[Fc];
  int bh = blockIdx.x;
  int b  = bh >> 3;
  int tid = threadIdx.x;
  for (int i = tid; i < Jc; i += 256) {
    Ssh[i] = sketch[b*Jc + i];
    sgn[i] = sign[b*Jc + i];
  }
  __syncthreads();
  for (int i = tid; i < Fc*Fc; i += 256) {
    int dd = i >> 7, e = i & 127;
    float vsum = 0.f;
    #pragma unroll
    for (int m = 0; m < Mc; ++m) {
      int t = Ssh[m*Fc + dd];
      vsum += sgn[m*Fc + dd] * AS[((size_t)bh*T2c + t)*Fc + e];
    }
    if (dd == e) vsum += 0.1f;
    stas[dd*129 + e] = vsum;
  }
  __syncthreads();
  if (tid < Fc) {
    float s = 0.f;
    for (int e = 0; e < Fc; ++e) s += stas[tid*129 + e];
    float di = 1.0f / sqrtf(s);
    Dl[tid] = di;
    Dinv[bh*Fc + tid] = di;
  }
  __syncthreads();
  for (int i = tid; i < Fc*Fc; i += 256) {
    int dd = i >> 7, e = i & 127;
    float vv = stas[dd*129 + e] * Dl[dd] * Dl[e];
    stas[dd*129 + e] = vv;
    STASn[(size_t)bh*Fc*Fc + i] = vv;
  }
  __syncthreads();
  if (tid < Fc) {
    float s = 0.f;
    for (int dd = 0; dd < Fc; ++dd) s += stas[dd*129 + tid];
    red[tid] = s;
  }
  __syncthreads();
  if (tid == 0) {
    float mx = 0.f;
    for (int e = 0; e < Fc; ++e) mx = fmaxf(mx, red[e]);
    atomicMax(gmax, __float_as_uint(mx));
  }
}

// ---------------- Newton-Schulz order-4, 3-way-split bf16 MFMA (fp32-class) ----------------
// V,Z live in LDS as fp32, stored TRANSPOSED: buf[a*LPF+b] = M[b][a]. B-operand
// fragment reads are exact; A-operand reads use symmetry (all iterates are
// polynomials in symmetric STASn; asymmetry ~fp32 rounding only).
// Each fragment is split on the fly: x = h + m + l (bf16 each, rne): rep err
// <= 2^-27. Product keeps {hh,hm,mh,hl,lh,mm}: dropped terms ~2^-27 => per-op
// backward error below fp32 eps. 6 MFMAs per 16x16x32 k-chunk.
constexpr int LPF = 132;   // fp32 padded row: bank=(4*row+ko)%32 -> uniform quads

__device__ __forceinline__ void split8(const f32x4& a, const f32x4& b,
                                       bf16x8& h, bf16x8& m, bf16x8& l) {
  float t[8] = {a[0],a[1],a[2],a[3],b[0],b[1],b[2],b[3]};
  #pragma unroll
  for (int j = 0; j < 8; ++j) {
    float x = t[j];
    unsigned short hb = f2bf_rne(x);
    float r1 = x - bf2f(hb);            // Sterbenz-exact
    unsigned short mb = f2bf_rne(r1);
    float r2 = r1 - bf2f(mb);           // exact
    h[j] = (short)hb; m[j] = (short)mb; l[j] = (short)f2bf_rne(r2);
  }
}

__device__ __forceinline__ void ld_split3(const float* __restrict__ buf, int row, int ko,
                                          bf16x8& h, bf16x8& m, bf16x8& l) {
  f32x4 a = *(const f32x4*)&buf[row*LPF + ko];
  f32x4 b = *(const f32x4*)&buf[row*LPF + ko + 4];
  split8(a, b, h, m, l);
}

__device__ __forceinline__ void mm6(const bf16x8 ah[2], const bf16x8 am[2], const bf16x8 al[2],
                                    const bf16x8 bh[4], const bf16x8 bm[4], const bf16x8 bl[4],
                                    f32x4 acc[2][4]) {
  #pragma unroll
  for (int m = 0; m < 2; ++m)
    #pragma unroll
    for (int n = 0; n < 4; ++n) {
      // small terms first for accumulate precision
      acc[m][n] = __builtin_amdgcn_mfma_f32_16x16x32_bf16(am[m], bm[n], acc[m][n], 0,0,0);
      acc[m][n] = __builtin_amdgcn_mfma_f32_16x16x32_bf16(ah[m], bl[n], acc[m][n], 0,0,0);
      acc[m][n] = __builtin_amdgcn_mfma_f32_16x16x32_bf16(al[m], bh[n], acc[m][n], 0,0,0);
      acc[m][n] = __builtin_amdgcn_mfma_f32_16x16x32_bf16(ah[m], bm[n], acc[m][n], 0,0,0);
      acc[m][n] = __builtin_amdgcn_mfma_f32_16x16x32_bf16(am[m], bh[n], acc[m][n], 0,0,0);
      acc[m][n] = __builtin_amdgcn_mfma_f32_16x16x32_bf16(ah[m], bh[n], acc[m][n], 0,0,0);
    }
}

__device__ __forceinline__ void mm_lds3(const float* __restrict__ A, const float* __restrict__ B,
                                        int R0, int C0, int l16, int lg, f32x4 acc[2][4]) {
  #pragma unroll 1
  for (int kc = 0; kc < Fc; kc += 32) {
    int ko = kc + lg*8;
    bf16x8 ah[2], am[2], al[2], bh[4], bm[4], bl[4];
    #pragma unroll
    for (int m = 0; m < 2; ++m)
      ld_split3(A, R0+16*m+l16, ko, ah[m], am[m], al[m]);
    #pragma unroll
    for (int n = 0; n < 4; ++n)
      ld_split3(B, C0+16*n+l16, ko, bh[n], bm[n], bl[n]);
    mm6(ah, am, al, bh, bm, bl, acc);
  }
}

__device__ __forceinline__ void mm_gl3(const float* __restrict__ Kp, const float* __restrict__ B,
                                       int R0, int C0, int l16, int lg, f32x4 acc[2][4]) {
  #pragma unroll 1
  for (int kc = 0; kc < Fc; kc += 32) {
    int ko = kc + lg*8;
    bf16x8 ah[2], am[2], al[2], bh[4], bm[4], bl[4];
    #pragma unroll
    for (int m = 0; m < 2; ++m) {
      const float* src = Kp + (R0+16*m+l16)*Fc + ko;   // direct row-major read
      f32x4 x0 = *(const f32x4*)(src);
      f32x4 x1 = *(const f32x4*)(src + 4);
      split8(x0, x1, ah[m], am[m], al[m]);
    }
    #pragma unroll
    for (int n = 0; n < 4; ++n)
      ld_split3(B, C0+16*n+l16, ko, bh[n], bm[n], bl[n]);
    mm6(ah, am, al, bh, bm, bl, acc);
  }
}

__device__ __forceinline__ void wb_f32(float* __restrict__ buf, int row0, int col, f32x4 v) {
  *(f32x4*)&buf[col*LPF + row0] = v;    // transposed store, 16B aligned (row0 % 4 == 0)
}

__global__ __launch_bounds__(512, 2) void newton_mfma_kernel(
    const float* __restrict__ STASn, const float* __restrict__ gmaxf,
    float* __restrict__ Vout) {
  extern __shared__ float smf[];
  float* Vf = smf;               // [128][LPF] fp32, transposed convention
  float* Zf = smf + 128*LPF;
  int bh = blockIdx.x;
  const float* Kp = STASn + (size_t)bh*Fc*Fc;
  float ginv = 1.0f / gmaxf[0];
  int tid  = threadIdx.x;
  int lane = tid & 63;
  int wid  = tid >> 6;        // 0..7
  int wr = wid >> 1, wc = wid & 1;
  int l16 = lane & 15, lg = lane >> 4;
  int R0 = wr*32, C0 = wc*64;
  int drow0 = lg*4;           // fragment row base within 16

  // V0 = K^T * ginv (K symmetric at fp32 level)
  f32x4 vreg[2][4];
  #pragma unroll
  for (int m = 0; m < 2; ++m)
    #pragma unroll
    for (int n = 0; n < 4; ++n) {
      int col = C0 + 16*n + l16;
      #pragma unroll
      for (int r = 0; r < 4; ++r)
        vreg[m][n][r] = Kp[(R0 + 16*m + drow0 + r)*Fc + col] * ginv;
      wb_f32(Vf, R0 + 16*m + drow0, col, vreg[m][n]);
    }
  __syncthreads();

  f32x4 fin[2][4];
  for (int it = 0; it < 6; ++it) {
    f32x4 acc[2][4];
    // P1: Z = K @ V
    #pragma unroll
    for (int m = 0; m < 2; ++m) for (int n = 0; n < 4; ++n) acc[m][n] = 0.f;
    mm_gl3(Kp, Vf, R0, C0, l16, lg, acc);
    #pragma unroll
    for (int m = 0; m < 2; ++m)
      #pragma unroll
      for (int n = 0; n < 4; ++n)
        wb_f32(Zf, R0 + 16*m + drow0, C0 + 16*n + l16, acc[m][n]);
    __syncthreads();

    // P2: W1 = V @ Z ; fin = 13V - 15W1
    #pragma unroll
    for (int m = 0; m < 2; ++m) for (int n = 0; n < 4; ++n) acc[m][n] = 0.f;
    mm_lds3(Vf, Zf, R0, C0, l16, lg, acc);
    #pragma unroll
    for (int m = 0; m < 2; ++m)
      #pragma unroll
      for (int n = 0; n < 4; ++n)
        fin[m][n] = 13.f*vreg[m][n] - 15.f*acc[m][n];
    __syncthreads();
    #pragma unroll
    for (int m = 0; m < 2; ++m)
      #pragma unroll
      for (int n = 0; n < 4; ++n)
        wb_f32(Vf, R0 + 16*m + drow0, C0 + 16*n + l16, acc[m][n]);
    __syncthreads();

    // P3: W2 = W1 @ Z ; fin += 7W2
    #pragma unroll
    for (int m = 0; m < 2; ++m) for (int n = 0; n < 4; ++n) acc[m][n] = 0.f;
    mm_lds3(Vf, Zf, R0, C0, l16, lg, acc);
    #pragma unroll
    for (int m = 0; m < 2; ++m)
      #pragma unroll
      for (int n = 0; n < 4; ++n)
        fin[m][n] += 7.f*acc[m][n];
    __syncthreads();
    #pragma unroll
    for (int m = 0; m < 2; ++m)
      #pragma unroll
      for (int n = 0; n < 4; ++n)
        wb_f32(Vf, R0 + 16*m + drow0, C0 + 16*n + l16, acc[m][n]);
    __syncthreads();

    // P4: W3 = W2 @ Z ; V <- 0.25(fin - W3)
    #pragma unroll
    for (int m = 0; m < 2; ++m) for (int n = 0; n < 4; ++n) acc[m][n] = 0.f;
    mm_lds3(Vf, Zf, R0, C0, l16, lg, acc);
    #pragma unroll
    for (int m = 0; m < 2; ++m)
      #pragma unroll
      for (int n = 0; n < 4; ++n) {
        fin[m][n] = 0.25f*(fin[m][n] - acc[m][n]);
        vreg[m][n] = fin[m][n];
      }
    __syncthreads();
    #pragma unroll
    for (int m = 0; m < 2; ++m)
      #pragma unroll
      for (int n = 0; n < 4; ++n)
        wb_f32(Vf, R0 + 16*m + drow0, C0 + 16*n + l16, fin[m][n]);
    __syncthreads();
  }

  // write V6 fp32
  float* Vo = Vout + (size_t)bh*Fc*Fc;
  #pragma unroll
  for (int m = 0; m < 2; ++m)
    #pragma unroll
    for (int n = 0; n < 4; ++n) {
      int col = C0 + 16*n + l16;
      #pragma unroll
      for (int r = 0; r < 4; ++r)
        Vo[(R0 + 16*m + drow0 + r)*Fc + col] = vreg[m][n][r];
    }
}

// ---------------- K-normalize in place ----------------
__global__ __launch_bounds__(256) void kn_kernel(
    float* __restrict__ AS, const float* __restrict__ Vinv,
    const float* __restrict__ Dinv, const float* __restrict__ mask) {
  extern __shared__ float sm[];
  float* Bs  = sm;            // [128][128]  Dinv[e]*STASinv[e][f]
  float* Asl = sm + Fc*Fc;    // [32][132]
  __shared__ float Dl[Fc];
  int bh = blockIdx.y;
  int b  = bh >> 3;
  int row0 = blockIdx.x * 32;
  int tid = threadIdx.x;
  int tr = tid >> 5, tc = tid & 31;
  if (tid < Fc) Dl[tid] = Dinv[bh*Fc + tid];
  __syncthreads();
  const float4* V4 = (const float4*)(Vinv + (size_t)bh*Fc*Fc);
  for (int i = tid; i < Fc*Fc/4; i += 256) {
    int e = i >> 5;
    float4 x = V4[i];
    float d = Dl[e];
    x.x*=d; x.y*=d; x.z*=d; x.w*=d;
    ((float4*)Bs)[i] = x;
  }
  for (int i = tid; i < 32*32; i += 256) {
    int r = i >> 5, kq = i & 31;
    float4 x = *(const float4*)(AS + ((size_t)bh*T2c + Nc + row0 + r)*Fc + kq*4);
    *(float4*)&Asl[r*132 + kq*4] = x;
  }
  __syncthreads();
  float acc[4][4] = {};
  #pragma unroll 2
  for (int e = 0; e < Fc; ++e) {
    float4 bv = *(const float4*)(Bs + e*Fc + tc*4);
    float a0 = Asl[(tr*4+0)*132 + e];
    float a1 = Asl[(tr*4+1)*132 + e];
    float a2 = Asl[(tr*4+2)*132 + e];
    float a3 = Asl[(tr*4+3)*132 + e];
    acc[0][0] += a0*bv.x; acc[0][1] += a0*bv.y; acc[0][2] += a0*bv.z; acc[0][3] += a0*bv.w;
    acc[1][0] += a1*bv.x; acc[1][1] += a1*bv.y; acc[1][2] += a1*bv.z; acc[1][3] += a1*bv.w;
    acc[2][0] += a2*bv.x; acc[2][1] += a2*bv.y; acc[2][2] += a2*bv.z; acc[2][3] += a2*bv.w;
    acc[3][0] += a3*bv.x; acc[3][1] += a3*bv.y; acc[3][2] += a3*bv.z; acc[3][3] += a3*bv.w;
  }
  #pragma unroll
  for (int i = 0; i < 4; ++i) {
    int row = row0 + tr*4 + i;
    float mk = mask[b*Nc + row];
    float4 o;
    o.x = acc[i][0]*Dl[tc*4+0]*mk;
    o.y = acc[i][1]*Dl[tc*4+1]*mk;
    o.z = acc[i][2]*Dl[tc*4+2]*mk;
    o.w = acc[i][3]*Dl[tc*4+3]*mk;
    *(float4*)(AS + ((size_t)bh*T2c + Nc + row)*Fc + tc*4) = o;
  }
}

// ---------------- context[f][e] = sum_t KN[t][f] * v[t][e] ----------------
__global__ __launch_bounds__(256) void ctx_kernel(
    const float* __restrict__ AS, const float* __restrict__ v,
    const float* __restrict__ mask, float* __restrict__ ctx) {
  __shared__ __align__(16) float KNs[32][132];
  __shared__ __align__(16) float vsl[32][68];
  int bh = blockIdx.y;
  int b  = bh >> 3;
  int t0 = blockIdx.x * 128;
  int tid = threadIdx.x;
  int tf = tid >> 3, te = tid & 7;
  float acc[4][8] = {};
  for (int sub = 0; sub < 4; ++sub) {
    __syncthreads();
    for (int i = tid; i < 32*32; i += 256) {
      int r = i >> 5, kq = i & 31;
      *(float4*)&KNs[r][kq*4] =
          *(const float4*)(AS + ((size_t)bh*T2c + Nc + t0 + sub*32 + r)*Fc + kq*4);
    }
    for (int i = tid; i < 32*16; i += 256) {
      int r = i >> 4, kq = i & 15;
      int t = t0 + sub*32 + r;
      float4 x = *(const float4*)(v + ((size_t)bh*Nc + t)*Dc + kq*4);
      float mk = mask[b*Nc + t];
      x.x*=mk; x.y*=mk; x.z*=mk; x.w*=mk;
      *(float4*)&vsl[r][kq*4] = x;
    }
    __syncthreads();
    #pragma unroll 2
    for (int tl = 0; tl < 32; ++tl) {
      float4 av = *(const float4*)&KNs[tl][tf*4];
      float4 b0 = *(const float4*)&vsl[tl][te*8];
      float4 b1 = *(const float4*)&vsl[tl][te*8+4];
      float a[4]  = {av.x, av.y, av.z, av.w};
      float bb[8] = {b0.x,b0.y,b0.z,b0.w,b1.x,b1.y,b1.z,b1.w};
      #pragma unroll
      for (int i = 0; i < 4; ++i)
        #pragma unroll
        for (int jj = 0; jj < 8; ++jj)
          acc[i][jj] += a[i]*bb[jj];
    }
  }
  #pragma unroll
  for (int i = 0; i < 4; ++i)
    #pragma unroll
    for (int jj = 0; jj < 8; ++jj)
      atomicAdd(ctx + (size_t)bh*Fc*Dc + (tf*4+i)*Dc + te*8 + jj, acc[i][jj]);
}

// ---------------- out = Q @ context ----------------
__global__ __launch_bounds__(256) void out_kernel(
    const float* __restrict__ AS, const float* __restrict__ ctx,
    float* __restrict__ out) {
  extern __shared__ float sm[];
  float* Asq = sm;             // [64][132]
  float* Cs  = sm + 64*132;    // [128][64]
  int bh = blockIdx.y;
  int row0 = blockIdx.x * 64;
  int tid = threadIdx.x;
  int tr = tid >> 4, tc = tid & 15;
  for (int i = tid; i < 64*32; i += 256) {
    int r = i >> 5, kq = i & 31;
    *(float4*)&Asq[r*132 + kq*4] =
        *(const float4*)(AS + ((size_t)bh*T2c + row0 + r)*Fc + kq*4);
  }
  for (int i = tid; i < 128*16; i += 256) {
    int r = i >> 4, kq = i & 15;
    *(float4*)&Cs[r*64 + kq*4] =
        *(const float4*)(ctx + (size_t)bh*Fc*Dc + r*Dc + kq*4);
  }
  __syncthreads();
  float acc[4][4] = {};
  #pragma unroll 2
  for (int kk = 0; kk < Fc; ++kk) {
    float4 bv = *(const float4*)&Cs[kk*64 + tc*4];
    float a0 = Asq[(tr*4+0)*132 + kk];
    float a1 = Asq[(tr*4+1)*132 + kk];
    float a2 = Asq[(tr*4+2)*132 + kk];
    float a3 = Asq[(tr*4+3)*132 + kk];
    acc[0][0] += a0*bv.x; acc[0][1] += a0*bv.y; acc[0][2] += a0*bv.z; acc[0][3] += a0*bv.w;
    acc[1][0] += a1*bv.x; acc[1][1] += a1*bv.y; acc[1][2] += a1*bv.z; acc[1][3] += a1*bv.w;
    acc[2][0] += a2*bv.x; acc[2][1] += a2*bv.y; acc[2][2] += a2*bv.z; acc[2][3] += a2*bv.w;
    acc[3][0] += a3*bv.x; acc[3][1] += a3*bv.y; acc[3][2] += a3*bv.z; acc[3][3] += a3*bv.w;
  }
  #pragma unroll
  for (int i = 0; i < 4; ++i) {
    float4 o;
    o.x = acc[i][0]; o.y = acc[i][1]; o.z = acc[i][2]; o.w = acc[i][3];
    *(float4*)(out + ((size_t)bh*Nc + row0 + tr*4 + i)*Dc + tc*4) = o;
  }
}

extern "C" void kernel_launch(void* const* d_in, const int* in_sizes, int n_in,
                              void* d_out, int out_size, void* d_ws, size_t ws_size,
                              hipStream_t stream) {
  const float* q    = (const float*)d_in[0];
  const float* k    = (const float*)d_in[1];
  const float* v    = (const float*)d_in[2];
  const float* mask = (const float*)d_in[3];
  const float* sign = (const float*)d_in[4];
  const int*   sketch = (const int*)d_in[5];
  float* out = (float*)d_out;
  float* ws  = (float*)d_ws;

  hipMemsetAsync(ws + OFF_GMAX, 0, sizeof(float), stream);
  hipMemsetAsync(ws + OFF_CTX, 0, (size_t)BHc*Fc*Dc*sizeof(float), stream);

  diag1_kernel<<<BHc*T2c*16/256, 256, 0, stream>>>(q, k, mask, ws + OFF_DIAG1);
  gather_kernel<<<BHc*Jc*16/256, 256, 0, stream>>>(q, k, mask, sketch, ws + OFF_DIAG1,
                                                   ws + OFF_XSG, ws + OFF_DIAG2);
  as_gemm_kernel<<<dim3(T2c/32, BHc), 256, 0, stream>>>(q, k, mask, ws + OFF_XSG,
      ws + OFF_DIAG1, ws + OFF_DIAG2, sign, ws + OFF_AS);
  stas_kernel<<<BHc, 256, 128*129*sizeof(float), stream>>>(ws + OFF_AS, sketch, sign,
      ws + OFF_STASN, ws + OFF_DINV, (unsigned int*)(ws + OFF_GMAX));
  newton_mfma_kernel<<<BHc, 512, 2*128*LPF*sizeof(float), stream>>>(
      ws + OFF_STASN, ws + OFF_GMAX, ws + OFF_VBUF);
  kn_kernel<<<dim3(Nc/32, BHc), 256, (Fc*Fc + 32*132)*sizeof(float), stream>>>(
      ws + OFF_AS, ws + OFF_VBUF, ws + OFF_DINV, mask);
  ctx_kernel<<<dim3(Nc/128, BHc), 256, 0, stream>>>(ws + OFF_AS, v, mask, ws + OFF_CTX);
  out_kernel<<<dim3(Nc/64, BHc), 256, (64*132 + 128*64)*sizeof(float), stream>>>(
      ws + OFF_AS, ws + OFF_CTX, out);
}

// Round 6
// 564.282 us; speedup vs baseline: 1.3669x; 1.2148x over previous
//
#include <hip/hip_runtime.h>

constexpr int Bc = 4, Hc = 8, Nc = 2048, Dc = 64, Fc = 128, Mc = 4;
constexpr int BHc = Bc*Hc;        // 32
constexpr int T2c = 2*Nc;         // 4096
constexpr int Jc  = Mc*Fc;        // 512
constexpr float DNORM = 0.4204482076268573f;   // 32^-0.25

// workspace offsets (in floats)
constexpr size_t OFF_AS    = 0;                                 // 16777216
constexpr size_t OFF_XSH   = OFF_AS    + (size_t)BHc*T2c*Fc;    // xs h-plane (ushort)
constexpr size_t OFF_XSM   = OFF_XSH   + (size_t)BHc*Jc*Dc/2;   // xs m-plane
constexpr size_t OFF_XSL   = OFF_XSM   + (size_t)BHc*Jc*Dc/2;   // xs l-plane
constexpr size_t OFF_DIAG1 = OFF_XSL   + (size_t)BHc*Jc*Dc/2;
constexpr size_t OFF_DIAG2 = OFF_DIAG1 + (size_t)BHc*T2c;
constexpr size_t OFF_STASN = OFF_DIAG2 + (size_t)BHc*Jc;
constexpr size_t OFF_VBUF  = OFF_STASN + (size_t)BHc*Fc*Fc;
constexpr size_t OFF_DINV  = OFF_VBUF  + (size_t)BHc*Fc*Fc;
constexpr size_t OFF_GMAX  = OFF_DINV  + (size_t)BHc*Fc;
constexpr size_t OFF_CTX   = OFF_GMAX  + 64;
constexpr size_t OFF_KH    = OFF_CTX   + (size_t)BHc*Fc*Dc;     // K h-plane (ushort)
constexpr size_t OFF_KM    = OFF_KH    + (size_t)BHc*Fc*Fc/2;
constexpr size_t OFF_KL    = OFF_KM    + (size_t)BHc*Fc*Fc/2;
// end = OFF_KL + BHc*Fc*Fc/2  ~= 82.4 MB

typedef __attribute__((ext_vector_type(8))) short bf16x8;
typedef __attribute__((ext_vector_type(4))) float f32x4;
typedef __attribute__((ext_vector_type(4))) unsigned short u16x4;

__device__ __forceinline__ unsigned short f2bf_rne(float x) {
  unsigned int u = __float_as_uint(x);
  u += 0x7fff + ((u >> 16) & 1);
  return (unsigned short)(u >> 16);
}
__device__ __forceinline__ float bf2f(unsigned short h) {
  return __uint_as_float(((unsigned int)h) << 16);
}

// ---------------- diag1: 0.5*|x_t|^2 for all rows of X = [q;k]*scale ----------------
__global__ __launch_bounds__(256) void diag1_kernel(
    const float* __restrict__ q, const float* __restrict__ k,
    const float* __restrict__ mask, float* __restrict__ diag1) {
  int gid = blockIdx.x*256 + threadIdx.x;     // over BH*T2*16
  int kq  = gid & 15;
  int row = gid >> 4;                         // bh*T2 + t
  int t   = row & (T2c - 1);
  int bh  = row >> 12;
  int b   = bh >> 3;
  int tn  = (t < Nc) ? t : t - Nc;
  const float* src = ((t < Nc) ? q : k) + ((size_t)bh*Nc + tn)*Dc;
  float sc = DNORM * mask[b*Nc + tn];
  float4 x = *(const float4*)(src + kq*4);
  float s = x.x*x.x + x.y*x.y + x.z*x.z + x.w*x.w;
  s += __shfl_xor(s, 1);
  s += __shfl_xor(s, 2);
  s += __shfl_xor(s, 4);
  s += __shfl_xor(s, 8);
  if (kq == 0) diag1[row] = 0.5f * sc * sc * s;
}

// ---------------- gather sketch rows -> pre-split bf16 h/m/l planes + diag2 ----------------
__global__ __launch_bounds__(256) void gather_kernel(
    const float* __restrict__ q, const float* __restrict__ k,
    const float* __restrict__ mask, const int* __restrict__ sketch,
    const float* __restrict__ diag1,
    unsigned short* __restrict__ xsh, unsigned short* __restrict__ xsm,
    unsigned short* __restrict__ xsl, float* __restrict__ diag2) {
  int gid = blockIdx.x*256 + threadIdx.x;     // over BH*J*16
  int kq  = gid & 15;
  int idx = gid >> 4;                         // bh*J + j
  int j   = idx & (Jc - 1);
  int bh  = idx >> 9;
  int b   = bh >> 3;
  int t   = sketch[b*Jc + j];
  int tn  = (t < Nc) ? t : t - Nc;
  const float* src = ((t < Nc) ? q : k) + ((size_t)bh*Nc + tn)*Dc;
  float sc = DNORM * mask[b*Nc + tn];
  float4 x = *(const float4*)(src + kq*4);
  float xv[4] = {x.x*sc, x.y*sc, x.z*sc, x.w*sc};
  u16x4 hh, mm_, ll;
  #pragma unroll
  for (int jj = 0; jj < 4; ++jj) {
    unsigned short h = f2bf_rne(xv[jj]);
    float r1 = xv[jj] - bf2f(h);
    unsigned short m = f2bf_rne(r1);
    float r2 = r1 - bf2f(m);
    hh[jj] = h; mm_[jj] = m; ll[jj] = f2bf_rne(r2);
  }
  *(u16x4*)(xsh + (size_t)idx*Dc + kq*4) = hh;
  *(u16x4*)(xsm + (size_t)idx*Dc + kq*4) = mm_;
  *(u16x4*)(xsl + (size_t)idx*Dc + kq*4) = ll;
  if (kq == 0) diag2[idx] = diag1[bh*T2c + t];
}

// ---------------- AS GEMM via MFMA, 3-way rne split, 6-term products ----------------
__global__ __launch_bounds__(256) void as_mfma_kernel(
    const float* __restrict__ q, const float* __restrict__ k,
    const float* __restrict__ mask,
    const unsigned short* __restrict__ xsh, const unsigned short* __restrict__ xsm,
    const unsigned short* __restrict__ xsl,
    const float* __restrict__ diag1, const float* __restrict__ diag2,
    const float* __restrict__ sign, float* __restrict__ AS) {
  __shared__ __align__(16) unsigned short Ah[64][72];
  __shared__ __align__(16) unsigned short Am[64][72];
  __shared__ __align__(16) unsigned short Al[64][72];
  __shared__ float d1s[64];
  __shared__ float d2s[4][128];
  __shared__ float sgs[4][128];
  int bh = blockIdx.y, b = bh >> 3;
  int t0 = blockIdx.x * 64;
  int tid = threadIdx.x;
  int lane = tid & 63, wid = tid >> 6;   // 4 waves
  int wr = wid >> 1, wc = wid & 1;
  int l16 = lane & 15, lg = lane >> 4;
  int R0 = wr*32, C0 = wc*64;

  // stage + 3-split A tile (64 rows x 64 k)
  for (int i = tid; i < 64*16; i += 256) {
    int r = i >> 4, kq = i & 15;
    int t = t0 + r;
    int tn = (t < Nc) ? t : t - Nc;
    const float* src = ((t < Nc) ? q : k) + ((size_t)bh*Nc + tn)*Dc + kq*4;
    float sc = DNORM * mask[b*Nc + tn];
    float4 x = *(const float4*)src;
    float xv[4] = {x.x*sc, x.y*sc, x.z*sc, x.w*sc};
    u16x4 hv, mv, lv;
    #pragma unroll
    for (int jj = 0; jj < 4; ++jj) {
      unsigned short h = f2bf_rne(xv[jj]);
      float r1 = xv[jj] - bf2f(h);
      unsigned short m = f2bf_rne(r1);
      float r2 = r1 - bf2f(m);
      hv[jj] = h; mv[jj] = m; lv[jj] = f2bf_rne(r2);
    }
    *(u16x4*)&Ah[r][kq*4] = hv;
    *(u16x4*)&Am[r][kq*4] = mv;
    *(u16x4*)&Al[r][kq*4] = lv;
  }
  if (tid < 64) d1s[tid] = diag1[bh*T2c + t0 + tid];
  for (int i = tid; i < 512; i += 256) {
    d2s[i>>7][i&127] = diag2[bh*Jc + i];
    sgs[i>>7][i&127] = sign[b*Jc + i];
  }
  __syncthreads();

  const unsigned short* xhh = xsh + (size_t)bh*Jc*Dc;
  const unsigned short* xmm = xsm + (size_t)bh*Jc*Dc;
  const unsigned short* xll = xsl + (size_t)bh*Jc*Dc;
  f32x4 oa[2][4];
  #pragma unroll
  for (int m = 0; m < 2; ++m)
    #pragma unroll
    for (int n = 0; n < 4; ++n) oa[m][n] = 0.f;

  for (int m = 0; m < Mc; ++m) {
    f32x4 acc[2][4];
    #pragma unroll
    for (int mm = 0; mm < 2; ++mm)
      #pragma unroll
      for (int nn = 0; nn < 4; ++nn) acc[mm][nn] = 0.f;
    #pragma unroll
    for (int kc = 0; kc < Dc; kc += 32) {
      int ko = kc + lg*8;
      bf16x8 ah[2], am2[2], al2[2], bhv[4], bmv[4], blv[4];
      #pragma unroll
      for (int mm = 0; mm < 2; ++mm) {
        ah[mm]  = *(const bf16x8*)&Ah[R0+16*mm+l16][ko];
        am2[mm] = *(const bf16x8*)&Am[R0+16*mm+l16][ko];
        al2[mm] = *(const bf16x8*)&Al[R0+16*mm+l16][ko];
      }
      #pragma unroll
      for (int nn = 0; nn < 4; ++nn) {
        size_t p = (size_t)(m*Fc + C0 + 16*nn + l16)*Dc + ko;
        bhv[nn] = *(const bf16x8*)(xhh + p);
        bmv[nn] = *(const bf16x8*)(xmm + p);
        blv[nn] = *(const bf16x8*)(xll + p);
      }
      #pragma unroll
      for (int mm = 0; mm < 2; ++mm)
        #pragma unroll
        for (int nn = 0; nn < 4; ++nn) {
          acc[mm][nn] = __builtin_amdgcn_mfma_f32_16x16x32_bf16(am2[mm], bmv[nn], acc[mm][nn], 0,0,0);
          acc[mm][nn] = __builtin_amdgcn_mfma_f32_16x16x32_bf16(ah[mm],  blv[nn], acc[mm][nn], 0,0,0);
          acc[mm][nn] = __builtin_amdgcn_mfma_f32_16x16x32_bf16(al2[mm], bhv[nn], acc[mm][nn], 0,0,0);
          acc[mm][nn] = __builtin_amdgcn_mfma_f32_16x16x32_bf16(ah[mm],  bmv[nn], acc[mm][nn], 0,0,0);
          acc[mm][nn] = __builtin_amdgcn_mfma_f32_16x16x32_bf16(am2[mm], bhv[nn], acc[mm][nn], 0,0,0);
          acc[mm][nn] = __builtin_amdgcn_mfma_f32_16x16x32_bf16(ah[mm],  bhv[nn], acc[mm][nn], 0,0,0);
        }
    }
    #pragma unroll
    for (int mm = 0; mm < 2; ++mm)
      #pragma unroll
      for (int nn = 0; nn < 4; ++nn) {
        int c = C0 + 16*nn + l16;
        float d2v = d2s[m][c], sg = sgs[m][c];
        #pragma unroll
        for (int r = 0; r < 4; ++r) {
          int row = R0 + 16*mm + 4*lg + r;
          oa[mm][nn][r] += sg * __expf(acc[mm][nn][r] - d1s[row] - d2v);
        }
      }
  }
  #pragma unroll
  for (int mm = 0; mm < 2; ++mm)
    #pragma unroll
    for (int nn = 0; nn < 4; ++nn) {
      int c = C0 + 16*nn + l16;
      #pragma unroll
      for (int r = 0; r < 4; ++r) {
        int row = R0 + 16*mm + 4*lg + r;
        AS[((size_t)bh*T2c + t0 + row)*Fc + c] = oa[mm][nn][r];
      }
    }
}

// ---------------- STAS build + normalize + K split planes + global colsum max ----------------
__global__ __launch_bounds__(256) void stas_kernel(
    const float* __restrict__ AS, const int* __restrict__ sketch,
    const float* __restrict__ sign,
    float* __restrict__ STASn, float* __restrict__ Dinv,
    unsigned short* __restrict__ Kh, unsigned short* __restrict__ Km,
    unsigned short* __restrict__ Kl,
    unsigned int* __restrict__ gmax) {
  extern __shared__ float stas[];   // [128][129] padded
  __shared__ int   Ssh[Jc];
  __shared__ float sgn[Jc];
  __shared__ float Dl[Fc];
  __shared__ float red[Fc];
  int bh = blockIdx.x;
  int b  = bh >> 3;
  int tid = threadIdx.x;
  for (int i = tid; i < Jc; i += 256) {
    Ssh[i] = sketch[b*Jc + i];
    sgn[i] = sign[b*Jc + i];
  }
  __syncthreads();
  for (int i = tid; i < Fc*Fc; i += 256) {
    int dd = i >> 7, e = i & 127;
    float vsum = 0.f;
    #pragma unroll
    for (int m = 0; m < Mc; ++m) {
      int t = Ssh[m*Fc + dd];
      vsum += sgn[m*Fc + dd] * AS[((size_t)bh*T2c + t)*Fc + e];
    }
    if (dd == e) vsum += 0.1f;
    stas[dd*129 + e] = vsum;
  }
  __syncthreads();
  if (tid < Fc) {
    float s = 0.f;
    for (int e = 0; e < Fc; ++e) s += stas[tid*129 + e];
    float di = 1.0f / sqrtf(s);
    Dl[tid] = di;
    Dinv[bh*Fc + tid] = di;
  }
  __syncthreads();
  for (int i = tid; i < Fc*Fc; i += 256) {
    int dd = i >> 7, e = i & 127;
    float vv = stas[dd*129 + e] * Dl[dd] * Dl[e];
    stas[dd*129 + e] = vv;
    STASn[(size_t)bh*Fc*Fc + i] = vv;
    unsigned short hb = f2bf_rne(vv); float r1 = vv - bf2f(hb);
    unsigned short mb = f2bf_rne(r1); float r2 = r1 - bf2f(mb);
    Kh[(size_t)bh*Fc*Fc + i] = hb;
    Km[(size_t)bh*Fc*Fc + i] = mb;
    Kl[(size_t)bh*Fc*Fc + i] = f2bf_rne(r2);
  }
  __syncthreads();
  if (tid < Fc) {
    float s = 0.f;
    for (int dd = 0; dd < Fc; ++dd) s += stas[dd*129 + tid];
    red[tid] = s;
  }
  __syncthreads();
  if (tid == 0) {
    float mx = 0.f;
    for (int e = 0; e < Fc; ++e) mx = fmaxf(mx, red[e]);
    atomicMax(gmax, __float_as_uint(mx));
  }
}

// ---------------- Newton-Schulz order-4 (round-3 math, round-4 layout) ----------------
// Convention: Af[a][b] = M[b][a] (transposed store). Reads at brow=row give M^T
// (A-side, symmetry); reads at brow=col give M exactly (B-side).
// P1: Z = K @ V  -- A = pre-split K planes read at ROWS (exact), B = Af at cols
//     (exact). NO symmetry reliance in P1; Z write-back pre-splits into LDS
//     planes (same bf16 values as split-on-read -> numerics == round 3).
// P2-P4: A = Af (fp32, split-on-read, symmetric read); B = Z planes (exact).
__device__ __forceinline__ unsigned aoff(int brow, int ke) {      // fp32 plane
  unsigned byte = ((unsigned)brow << 9) | ((unsigned)ke << 2);
  return byte ^ (((unsigned)(brow & 7)) << 4);
}
__device__ __forceinline__ unsigned boff(int brow, int ke) {      // bf16 plane
  unsigned byte = ((unsigned)brow << 8) | ((unsigned)ke << 1);
  return byte ^ (((unsigned)(brow & 7)) << 4);
}

__device__ __forceinline__ void split8(const f32x4& a, const f32x4& b,
                                       bf16x8& h, bf16x8& m, bf16x8& l) {
  float t[8] = {a[0],a[1],a[2],a[3],b[0],b[1],b[2],b[3]};
  #pragma unroll
  for (int j = 0; j < 8; ++j) {
    float x = t[j];
    unsigned short hb = f2bf_rne(x);
    float r1 = x - bf2f(hb);
    unsigned short mb = f2bf_rne(r1);
    float r2 = r1 - bf2f(mb);
    h[j] = (short)hb; m[j] = (short)mb; l[j] = (short)f2bf_rne(r2);
  }
}

__device__ __forceinline__ void ld_splitA(const char* Af, int brow, int ko,
                                          bf16x8& h, bf16x8& m, bf16x8& l) {
  f32x4 a = *(const f32x4*)(Af + aoff(brow, ko));
  f32x4 b = *(const f32x4*)(Af + aoff(brow, ko + 4));
  split8(a, b, h, m, l);
}

__device__ __forceinline__ void mm6(const bf16x8 ah[2], const bf16x8 am[2], const bf16x8 al[2],
                                    const bf16x8 bh[4], const bf16x8 bm[4], const bf16x8 bl[4],
                                    f32x4 acc[2][4]) {
  #pragma unroll
  for (int m = 0; m < 2; ++m)
    #pragma unroll
    for (int n = 0; n < 4; ++n) {
      acc[m][n] = __builtin_amdgcn_mfma_f32_16x16x32_bf16(am[m], bm[n], acc[m][n], 0,0,0);
      acc[m][n] = __builtin_amdgcn_mfma_f32_16x16x32_bf16(ah[m], bl[n], acc[m][n], 0,0,0);
      acc[m][n] = __builtin_amdgcn_mfma_f32_16x16x32_bf16(al[m], bh[n], acc[m][n], 0,0,0);
      acc[m][n] = __builtin_amdgcn_mfma_f32_16x16x32_bf16(ah[m], bm[n], acc[m][n], 0,0,0);
      acc[m][n] = __builtin_amdgcn_mfma_f32_16x16x32_bf16(am[m], bh[n], acc[m][n], 0,0,0);
      acc[m][n] = __builtin_amdgcn_mfma_f32_16x16x32_bf16(ah[m], bh[n], acc[m][n], 0,0,0);
    }
}

// P1: Z = K @ V. A-fragments from global pre-split K planes at ROWS (exact);
// B-fragments from Af at brow=col (exact V read).
__device__ __forceinline__ void mm_p1(
    const unsigned short* __restrict__ kh, const unsigned short* __restrict__ km,
    const unsigned short* __restrict__ kl, const char* Af,
    int R0, int C0, int l16, int lg, f32x4 acc[2][4]) {
  #pragma unroll 1
  for (int kc = 0; kc < Fc; kc += 32) {
    int ko = kc + lg*8;
    bf16x8 ah[2], am[2], al[2], bh[4], bm[4], bl[4];
    #pragma unroll
    for (int m = 0; m < 2; ++m) {
      size_t p = (size_t)(R0+16*m+l16)*Fc + ko;
      ah[m] = *(const bf16x8*)(kh + p);
      am[m] = *(const bf16x8*)(km + p);
      al[m] = *(const bf16x8*)(kl + p);
    }
    #pragma unroll
    for (int n = 0; n < 4; ++n)
      ld_splitA(Af, C0+16*n+l16, ko, bh[n], bm[n], bl[n]);
    mm6(ah, am, al, bh, bm, bl, acc);
  }
}

// P2-P4: A = Af at brow=row (symmetric read, split on the fly); B = Z planes (exact).
__device__ __forceinline__ void mm_ldsB(const char* Af,
    const char* Zh, const char* Zm, const char* Zl,
    int R0, int C0, int l16, int lg, f32x4 acc[2][4]) {
  #pragma unroll 1
  for (int kc = 0; kc < Fc; kc += 32) {
    int ko = kc + lg*8;
    bf16x8 ah[2], am[2], al[2], bh[4], bm[4], bl[4];
    #pragma unroll
    for (int m = 0; m < 2; ++m)
      ld_splitA(Af, R0+16*m+l16, ko, ah[m], am[m], al[m]);
    #pragma unroll
    for (int n = 0; n < 4; ++n) {
      unsigned off = boff(C0+16*n+l16, ko);
      bh[n] = *(const bf16x8*)(Zh + off);
      bm[n] = *(const bf16x8*)(Zm + off);
      bl[n] = *(const bf16x8*)(Zl + off);
    }
    mm6(ah, am, al, bh, bm, bl, acc);
  }
}

__device__ __forceinline__ void wbA(char* Af, int col, int row0, f32x4 v) {
  *(f32x4*)(Af + aoff(col, row0)) = v;        // Af[col][row] = M[row][col]
}
__device__ __forceinline__ void wbZ(char* Zh, char* Zm, char* Zl,
                                    int col, int row0, f32x4 v) {
  u16x4 hv, mv, lv;
  #pragma unroll
  for (int r = 0; r < 4; ++r) {
    unsigned short hb = f2bf_rne(v[r]); float r1 = v[r] - bf2f(hb);
    unsigned short mb = f2bf_rne(r1);   float r2 = r1 - bf2f(mb);
    hv[r] = hb; mv[r] = mb; lv[r] = f2bf_rne(r2);
  }
  unsigned off = boff(col, row0);             // Zbuf[col][row] = split(Z[row][col])
  *(u16x4*)(Zh + off) = hv;
  *(u16x4*)(Zm + off) = mv;
  *(u16x4*)(Zl + off) = lv;
}

__global__ __launch_bounds__(512) void newton_mfma_kernel(
    const float* __restrict__ STASn,
    const unsigned short* __restrict__ KhG, const unsigned short* __restrict__ KmG,
    const unsigned short* __restrict__ KlG,
    const float* __restrict__ gmaxf, float* __restrict__ Vout) {
  extern __shared__ char smc[];
  char* Zh = smc;
  char* Zm = smc + 32768;
  char* Zl = smc + 65536;
  char* Af = smc + 98304;
  int bh = blockIdx.x;
  const float* Kp = STASn + (size_t)bh*Fc*Fc;
  const unsigned short* kh = KhG + (size_t)bh*Fc*Fc;
  const unsigned short* km = KmG + (size_t)bh*Fc*Fc;
  const unsigned short* kl = KlG + (size_t)bh*Fc*Fc;
  float ginv = 1.0f / gmaxf[0];
  int tid  = threadIdx.x;
  int lane = tid & 63;
  int wid  = tid >> 6;        // 0..7
  int wr = wid >> 1, wc = wid & 1;
  int l16 = lane & 15, lg = lane >> 4;
  int R0 = wr*32, C0 = wc*64;
  int drow0 = lg*4;

  // V0 = K * ginv (K symmetric at fp32 level); store transposed into Af
  f32x4 vreg[2][4];
  #pragma unroll
  for (int m = 0; m < 2; ++m)
    #pragma unroll
    for (int n = 0; n < 4; ++n) {
      int col = C0 + 16*n + l16;
      #pragma unroll
      for (int r = 0; r < 4; ++r)
        vreg[m][n][r] = Kp[(size_t)(R0 + 16*m + drow0 + r)*Fc + col] * ginv;
      wbA(Af, col, R0 + 16*m + drow0, vreg[m][n]);
    }
  __syncthreads();

  f32x4 fin[2][4];
  for (int it = 0; it < 6; ++it) {
    f32x4 acc[2][4];
    // P1: Z = K @ V  (both operands exact)
    #pragma unroll
    for (int m = 0; m < 2; ++m) for (int n = 0; n < 4; ++n) acc[m][n] = 0.f;
    mm_p1(kh, km, kl, Af, R0, C0, l16, lg, acc);
    #pragma unroll
    for (int m = 0; m < 2; ++m)
      #pragma unroll
      for (int n = 0; n < 4; ++n)
        wbZ(Zh, Zm, Zl, C0 + 16*n + l16, R0 + 16*m + drow0, acc[m][n]);
    __syncthreads();

    // P2: W1 = V @ Z ; fin = 13V - 15W1
    #pragma unroll
    for (int m = 0; m < 2; ++m) for (int n = 0; n < 4; ++n) acc[m][n] = 0.f;
    mm_ldsB(Af, Zh, Zm, Zl, R0, C0, l16, lg, acc);
    #pragma unroll
    for (int m = 0; m < 2; ++m)
      #pragma unroll
      for (int n = 0; n < 4; ++n)
        fin[m][n] = 13.f*vreg[m][n] - 15.f*acc[m][n];
    __syncthreads();
    #pragma unroll
    for (int m = 0; m < 2; ++m)
      #pragma unroll
      for (int n = 0; n < 4; ++n)
        wbA(Af, C0 + 16*n + l16, R0 + 16*m + drow0, acc[m][n]);
    __syncthreads();

    // P3: W2 = W1 @ Z ; fin += 7W2
    #pragma unroll
    for (int m = 0; m < 2; ++m) for (int n = 0; n < 4; ++n) acc[m][n] = 0.f;
    mm_ldsB(Af, Zh, Zm, Zl, R0, C0, l16, lg, acc);
    #pragma unroll
    for (int m = 0; m < 2; ++m)
      #pragma unroll
      for (int n = 0; n < 4; ++n)
        fin[m][n] += 7.f*acc[m][n];
    __syncthreads();
    #pragma unroll
    for (int m = 0; m < 2; ++m)
      #pragma unroll
      for (int n = 0; n < 4; ++n)
        wbA(Af, C0 + 16*n + l16, R0 + 16*m + drow0, acc[m][n]);
    __syncthreads();

    // P4: W3 = W2 @ Z ; V <- 0.25(fin - W3)
    #pragma unroll
    for (int m = 0; m < 2; ++m) for (int n = 0; n < 4; ++n) acc[m][n] = 0.f;
    mm_ldsB(Af, Zh, Zm, Zl, R0, C0, l16, lg, acc);
    #pragma unroll
    for (int m = 0; m < 2; ++m)
      #pragma unroll
      for (int n = 0; n < 4; ++n) {
        fin[m][n] = 0.25f*(fin[m][n] - acc[m][n]);
        vreg[m][n] = fin[m][n];
      }
    __syncthreads();
    #pragma unroll
    for (int m = 0; m < 2; ++m)
      #pragma unroll
      for (int n = 0; n < 4; ++n)
        wbA(Af, C0 + 16*n + l16, R0 + 16*m + drow0, fin[m][n]);
    __syncthreads();
  }

  float* Vo = Vout + (size_t)bh*Fc*Fc;
  #pragma unroll
  for (int m = 0; m < 2; ++m)
    #pragma unroll
    for (int n = 0; n < 4; ++n) {
      int col = C0 + 16*n + l16;
      #pragma unroll
      for (int r = 0; r < 4; ++r)
        Vo[(size_t)(R0 + 16*m + drow0 + r)*Fc + col] = vreg[m][n][r];
    }
}

// ---------------- K-normalize in place ----------------
__global__ __launch_bounds__(256) void kn_kernel(
    float* __restrict__ AS, const float* __restrict__ Vinv,
    const float* __restrict__ Dinv, const float* __restrict__ mask) {
  extern __shared__ float sm[];
  float* Bs  = sm;            // [128][128]  Dinv[e]*STASinv[e][f]
  float* Asl = sm + Fc*Fc;    // [32][132]
  __shared__ float Dl[Fc];
  int bh = blockIdx.y;
  int b  = bh >> 3;
  int row0 = blockIdx.x * 32;
  int tid = threadIdx.x;
  int tr = tid >> 5, tc = tid & 31;
  if (tid < Fc) Dl[tid] = Dinv[bh*Fc + tid];
  __syncthreads();
  const float4* V4 = (const float4*)(Vinv + (size_t)bh*Fc*Fc);
  for (int i = tid; i < Fc*Fc/4; i += 256) {
    int e = i >> 5;
    float4 x = V4[i];
    float d = Dl[e];
    x.x*=d; x.y*=d; x.z*=d; x.w*=d;
    ((float4*)Bs)[i] = x;
  }
  for (int i = tid; i < 32*32; i += 256) {
    int r = i >> 5, kq = i & 31;
    float4 x = *(const float4*)(AS + ((size_t)bh*T2c + Nc + row0 + r)*Fc + kq*4);
    *(float4*)&Asl[r*132 + kq*4] = x;
  }
  __syncthreads();
  float acc[4][4] = {};
  #pragma unroll 2
  for (int e = 0; e < Fc; ++e) {
    float4 bv = *(const float4*)(Bs + e*Fc + tc*4);
    float a0 = Asl[(tr*4+0)*132 + e];
    float a1 = Asl[(tr*4+1)*132 + e];
    float a2 = Asl[(tr*4+2)*132 + e];
    float a3 = Asl[(tr*4+3)*132 + e];
    acc[0][0] += a0*bv.x; acc[0][1] += a0*bv.y; acc[0][2] += a0*bv.z; acc[0][3] += a0*bv.w;
    acc[1][0] += a1*bv.x; acc[1][1] += a1*bv.y; acc[1][2] += a1*bv.z; acc[1][3] += a1*bv.w;
    acc[2][0] += a2*bv.x; acc[2][1] += a2*bv.y; acc[2][2] += a2*bv.z; acc[2][3] += a2*bv.w;
    acc[3][0] += a3*bv.x; acc[3][1] += a3*bv.y; acc[3][2] += a3*bv.z; acc[3][3] += a3*bv.w;
  }
  #pragma unroll
  for (int i = 0; i < 4; ++i) {
    int row = row0 + tr*4 + i;
    float mk = mask[b*Nc + row];
    float4 o;
    o.x = acc[i][0]*Dl[tc*4+0]*mk;
    o.y = acc[i][1]*Dl[tc*4+1]*mk;
    o.z = acc[i][2]*Dl[tc*4+2]*mk;
    o.w = acc[i][3]*Dl[tc*4+3]*mk;
    *(float4*)(AS + ((size_t)bh*T2c + Nc + row)*Fc + tc*4) = o;
  }
}

// ---------------- context[f][e] = sum_t KN[t][f] * v[t][e] ----------------
__global__ __launch_bounds__(256) void ctx_kernel(
    const float* __restrict__ AS, const float* __restrict__ v,
    const float* __restrict__ mask, float* __restrict__ ctx) {
  __shared__ __align__(16) float KNs[32][132];
  __shared__ __align__(16) float vsl[32][68];
  int bh = blockIdx.y;
  int b  = bh >> 3;
  int t0 = blockIdx.x * 128;
  int tid = threadIdx.x;
  int tf = tid >> 3, te = tid & 7;
  float acc[4][8] = {};
  for (int sub = 0; sub < 4; ++sub) {
    __syncthreads();
    for (int i = tid; i < 32*32; i += 256) {
      int r = i >> 5, kq = i & 31;
      *(float4*)&KNs[r][kq*4] =
          *(const float4*)(AS + ((size_t)bh*T2c + Nc + t0 + sub*32 + r)*Fc + kq*4);
    }
    for (int i = tid; i < 32*16; i += 256) {
      int r = i >> 4, kq = i & 15;
      int t = t0 + sub*32 + r;
      float4 x = *(const float4*)(v + ((size_t)bh*Nc + t)*Dc + kq*4);
      float mk = mask[b*Nc + t];
      x.x*=mk; x.y*=mk; x.z*=mk; x.w*=mk;
      *(float4*)&vsl[r][kq*4] = x;
    }
    __syncthreads();
    #pragma unroll 2
    for (int tl = 0; tl < 32; ++tl) {
      float4 av = *(const float4*)&KNs[tl][tf*4];
      float4 b0 = *(const float4*)&vsl[tl][te*8];
      float4 b1 = *(const float4*)&vsl[tl][te*8+4];
      float a[4]  = {av.x, av.y, av.z, av.w};
      float bb[8] = {b0.x,b0.y,b0.z,b0.w,b1.x,b1.y,b1.z,b1.w};
      #pragma unroll
      for (int i = 0; i < 4; ++i)
        #pragma unroll
        for (int jj = 0; jj < 8; ++jj)
          acc[i][jj] += a[i]*bb[jj];
    }
  }
  #pragma unroll
  for (int i = 0; i < 4; ++i)
    #pragma unroll
    for (int jj = 0; jj < 8; ++jj)
      atomicAdd(ctx + (size_t)bh*Fc*Dc + (tf*4+i)*Dc + te*8 + jj, acc[i][jj]);
}

// ---------------- out = Q @ context ----------------
__global__ __launch_bounds__(256) void out_kernel(
    const float* __restrict__ AS, const float* __restrict__ ctx,
    float* __restrict__ out) {
  extern __shared__ float smo[];
  float* Asq = smo;            // [64][132]
  float* Cs  = smo + 64*132;   // [128][64]
  int bh = blockIdx.y;
  int row0 = blockIdx.x * 64;
  int tid = threadIdx.x;
  int tr = tid >> 4, tc = tid & 15;
  for (int i = tid; i < 64*32; i += 256) {
    int r = i >> 5, kq = i & 31;
    *(float4*)&Asq[r*132 + kq*4] =
        *(const float4*)(AS + ((size_t)bh*T2c + row0 + r)*Fc + kq*4);
  }
  for (int i = tid; i < 128*16; i += 256) {
    int r = i >> 4, kq = i & 15;
    *(float4*)&Cs[r*64 + kq*4] =
        *(const float4*)(ctx + (size_t)bh*Fc*Dc + r*Dc + kq*4);
  }
  __syncthreads();
  float acc[4][4] = {};
  #pragma unroll 2
  for (int kk = 0; kk < Fc; ++kk) {
    float4 bv = *(const float4*)&Cs[kk*64 + tc*4];
    float a0 = Asq[(tr*4+0)*132 + kk];
    float a1 = Asq[(tr*4+1)*132 + kk];
    float a2 = Asq[(tr*4+2)*132 + kk];
    float a3 = Asq[(tr*4+3)*132 + kk];
    acc[0][0] += a0*bv.x; acc[0][1] += a0*bv.y; acc[0][2] += a0*bv.z; acc[0][3] += a0*bv.w;
    acc[1][0] += a1*bv.x; acc[1][1] += a1*bv.y; acc[1][2] += a1*bv.z; acc[1][3] += a1*bv.w;
    acc[2][0] += a2*bv.x; acc[2][1] += a2*bv.y; acc[2][2] += a2*bv.z; acc[2][3] += a2*bv.w;
    acc[3][0] += a3*bv.x; acc[3][1] += a3*bv.y; acc[3][2] += a3*bv.z; acc[3][3] += a3*bv.w;
  }
  #pragma unroll
  for (int i = 0; i < 4; ++i) {
    float4 o;
    o.x = acc[i][0]; o.y = acc[i][1]; o.z = acc[i][2]; o.w = acc[i][3];
    *(float4*)(out + ((size_t)bh*Nc + row0 + tr*4 + i)*Dc + tc*4) = o;
  }
}

extern "C" void kernel_launch(void* const* d_in, const int* in_sizes, int n_in,
                              void* d_out, int out_size, void* d_ws, size_t ws_size,
                              hipStream_t stream) {
  const float* q    = (const float*)d_in[0];
  const float* k    = (const float*)d_in[1];
  const float* v    = (const float*)d_in[2];
  const float* mask = (const float*)d_in[3];
  const float* sign = (const float*)d_in[4];
  const int*   sketch = (const int*)d_in[5];
  float* out = (float*)d_out;
  float* ws  = (float*)d_ws;

  unsigned short* xsh = (unsigned short*)(ws + OFF_XSH);
  unsigned short* xsm = (unsigned short*)(ws + OFF_XSM);
  unsigned short* xsl = (unsigned short*)(ws + OFF_XSL);
  unsigned short* kh  = (unsigned short*)(ws + OFF_KH);
  unsigned short* km  = (unsigned short*)(ws + OFF_KM);
  unsigned short* kl  = (unsigned short*)(ws + OFF_KL);

  hipMemsetAsync(ws + OFF_GMAX, 0, sizeof(float), stream);
  hipMemsetAsync(ws + OFF_CTX, 0, (size_t)BHc*Fc*Dc*sizeof(float), stream);

  diag1_kernel<<<BHc*T2c*16/256, 256, 0, stream>>>(q, k, mask, ws + OFF_DIAG1);
  gather_kernel<<<BHc*Jc*16/256, 256, 0, stream>>>(q, k, mask, sketch, ws + OFF_DIAG1,
                                                   xsh, xsm, xsl, ws + OFF_DIAG2);
  as_mfma_kernel<<<dim3(T2c/64, BHc), 256, 0, stream>>>(q, k, mask, xsh, xsm, xsl,
      ws + OFF_DIAG1, ws + OFF_DIAG2, sign, ws + OFF_AS);
  stas_kernel<<<BHc, 256, 128*129*sizeof(float), stream>>>(ws + OFF_AS, sketch, sign,
      ws + OFF_STASN, ws + OFF_DINV, kh, km, kl, (unsigned int*)(ws + OFF_GMAX));
  newton_mfma_kernel<<<BHc, 512, 163840, stream>>>(ws + OFF_STASN, kh, km, kl,
      ws + OFF_GMAX, ws + OFF_VBUF);
  kn_kernel<<<dim3(Nc/32, BHc), 256, (Fc*Fc + 32*132)*sizeof(float), stream>>>(
      ws + OFF_AS, ws + OFF_VBUF, ws + OFF_DINV, mask);
  ctx_kernel<<<dim3(Nc/128, BHc), 256, 0, stream>>>(ws + OFF_AS, v, mask, ws + OFF_CTX);
  out_kernel<<<dim3(Nc/64, BHc), 256, (64*132 + 128*64)*sizeof(float), stream>>>(
      ws + OFF_AS, ws + OFF_CTX, out);
}

// Round 7
// 379.383 us; speedup vs baseline: 2.0330x; 1.4874x over previous
//
#include <hip/hip_runtime.h>

constexpr int Bc = 4, Hc = 8, Nc = 2048, Dc = 64, Fc = 128, Mc = 4;
constexpr int BHc = Bc*Hc;        // 32
constexpr int T2c = 2*Nc;         // 4096
constexpr int Jc  = Mc*Fc;        // 512
constexpr float DNORM = 0.4204482076268573f;   // 32^-0.25

// workspace offsets (in floats)
constexpr size_t OFF_AS    = 0;                                 // 16777216
constexpr size_t OFF_XSH   = OFF_AS    + (size_t)BHc*T2c*Fc;    // xs h-plane (ushort)
constexpr size_t OFF_XSM   = OFF_XSH   + (size_t)BHc*Jc*Dc/2;   // xs m-plane
constexpr size_t OFF_XSL   = OFF_XSM   + (size_t)BHc*Jc*Dc/2;   // xs l-plane
constexpr size_t OFF_DIAG1 = OFF_XSL   + (size_t)BHc*Jc*Dc/2;
constexpr size_t OFF_DIAG2 = OFF_DIAG1 + (size_t)BHc*T2c;
constexpr size_t OFF_STASN = OFF_DIAG2 + (size_t)BHc*Jc;
constexpr size_t OFF_VBUF  = OFF_STASN + (size_t)BHc*Fc*Fc;
constexpr size_t OFF_DINV  = OFF_VBUF  + (size_t)BHc*Fc*Fc;
constexpr size_t OFF_GMAX  = OFF_DINV  + (size_t)BHc*Fc;
constexpr size_t OFF_CTX   = OFF_GMAX  + 64;
constexpr size_t OFF_KH    = OFF_CTX   + (size_t)BHc*Fc*Dc;     // K h-plane (ushort)
constexpr size_t OFF_KM    = OFF_KH    + (size_t)BHc*Fc*Fc/2;
constexpr size_t OFF_KL    = OFF_KM    + (size_t)BHc*Fc*Fc/2;
// G_part reuses the xs-plane region (dead after as_mfma):
constexpr size_t OFF_GPART = OFF_XSH;   // [BHc][4][128][64] = 1,048,576 floats (fits 1,572,864)

typedef __attribute__((ext_vector_type(8))) short bf16x8;
typedef __attribute__((ext_vector_type(4))) float f32x4;
typedef __attribute__((ext_vector_type(4))) unsigned short u16x4;

__device__ __forceinline__ unsigned short f2bf_rne(float x) {
  unsigned int u = __float_as_uint(x);
  u += 0x7fff + ((u >> 16) & 1);
  return (unsigned short)(u >> 16);
}
__device__ __forceinline__ float bf2f(unsigned short h) {
  return __uint_as_float(((unsigned int)h) << 16);
}

// ---------------- diag1 ----------------
__global__ __launch_bounds__(256) void diag1_kernel(
    const float* __restrict__ q, const float* __restrict__ k,
    const float* __restrict__ mask, float* __restrict__ diag1) {
  int gid = blockIdx.x*256 + threadIdx.x;
  int kq  = gid & 15;
  int row = gid >> 4;
  int t   = row & (T2c - 1);
  int bh  = row >> 12;
  int b   = bh >> 3;
  int tn  = (t < Nc) ? t : t - Nc;
  const float* src = ((t < Nc) ? q : k) + ((size_t)bh*Nc + tn)*Dc;
  float sc = DNORM * mask[b*Nc + tn];
  float4 x = *(const float4*)(src + kq*4);
  float s = x.x*x.x + x.y*x.y + x.z*x.z + x.w*x.w;
  s += __shfl_xor(s, 1);
  s += __shfl_xor(s, 2);
  s += __shfl_xor(s, 4);
  s += __shfl_xor(s, 8);
  if (kq == 0) diag1[row] = 0.5f * sc * sc * s;
}

// ---------------- gather -> pre-split bf16 h/m/l planes + diag2 ----------------
__global__ __launch_bounds__(256) void gather_kernel(
    const float* __restrict__ q, const float* __restrict__ k,
    const float* __restrict__ mask, const int* __restrict__ sketch,
    const float* __restrict__ diag1,
    unsigned short* __restrict__ xsh, unsigned short* __restrict__ xsm,
    unsigned short* __restrict__ xsl, float* __restrict__ diag2) {
  int gid = blockIdx.x*256 + threadIdx.x;
  int kq  = gid & 15;
  int idx = gid >> 4;
  int j   = idx & (Jc - 1);
  int bh  = idx >> 9;
  int b   = bh >> 3;
  int t   = sketch[b*Jc + j];
  int tn  = (t < Nc) ? t : t - Nc;
  const float* src = ((t < Nc) ? q : k) + ((size_t)bh*Nc + tn)*Dc;
  float sc = DNORM * mask[b*Nc + tn];
  float4 x = *(const float4*)(src + kq*4);
  float xv[4] = {x.x*sc, x.y*sc, x.z*sc, x.w*sc};
  u16x4 hh, mm_, ll;
  #pragma unroll
  for (int jj = 0; jj < 4; ++jj) {
    unsigned short h = f2bf_rne(xv[jj]);
    float r1 = xv[jj] - bf2f(h);
    unsigned short m = f2bf_rne(r1);
    float r2 = r1 - bf2f(m);
    hh[jj] = h; mm_[jj] = m; ll[jj] = f2bf_rne(r2);
  }
  *(u16x4*)(xsh + (size_t)idx*Dc + kq*4) = hh;
  *(u16x4*)(xsm + (size_t)idx*Dc + kq*4) = mm_;
  *(u16x4*)(xsl + (size_t)idx*Dc + kq*4) = ll;
  if (kq == 0) diag2[idx] = diag1[bh*T2c + t];
}

// ---------------- AS GEMM via MFMA, 3-way rne split ----------------
__global__ __launch_bounds__(256) void as_mfma_kernel(
    const float* __restrict__ q, const float* __restrict__ k,
    const float* __restrict__ mask,
    const unsigned short* __restrict__ xsh, const unsigned short* __restrict__ xsm,
    const unsigned short* __restrict__ xsl,
    const float* __restrict__ diag1, const float* __restrict__ diag2,
    const float* __restrict__ sign, float* __restrict__ AS) {
  __shared__ __align__(16) unsigned short Ah[64][72];
  __shared__ __align__(16) unsigned short Am[64][72];
  __shared__ __align__(16) unsigned short Al[64][72];
  __shared__ float d1s[64];
  __shared__ float d2s[4][128];
  __shared__ float sgs[4][128];
  int bh = blockIdx.y, b = bh >> 3;
  int t0 = blockIdx.x * 64;
  int tid = threadIdx.x;
  int lane = tid & 63, wid = tid >> 6;
  int wr = wid >> 1, wc = wid & 1;
  int l16 = lane & 15, lg = lane >> 4;
  int R0 = wr*32, C0 = wc*64;

  for (int i = tid; i < 64*16; i += 256) {
    int r = i >> 4, kq = i & 15;
    int t = t0 + r;
    int tn = (t < Nc) ? t : t - Nc;
    const float* src = ((t < Nc) ? q : k) + ((size_t)bh*Nc + tn)*Dc + kq*4;
    float sc = DNORM * mask[b*Nc + tn];
    float4 x = *(const float4*)src;
    float xv[4] = {x.x*sc, x.y*sc, x.z*sc, x.w*sc};
    u16x4 hv, mv, lv;
    #pragma unroll
    for (int jj = 0; jj < 4; ++jj) {
      unsigned short h = f2bf_rne(xv[jj]);
      float r1 = xv[jj] - bf2f(h);
      unsigned short m = f2bf_rne(r1);
      float r2 = r1 - bf2f(m);
      hv[jj] = h; mv[jj] = m; lv[jj] = f2bf_rne(r2);
    }
    *(u16x4*)&Ah[r][kq*4] = hv;
    *(u16x4*)&Am[r][kq*4] = mv;
    *(u16x4*)&Al[r][kq*4] = lv;
  }
  if (tid < 64) d1s[tid] = diag1[bh*T2c + t0 + tid];
  for (int i = tid; i < 512; i += 256) {
    d2s[i>>7][i&127] = diag2[bh*Jc + i];
    sgs[i>>7][i&127] = sign[b*Jc + i];
  }
  __syncthreads();

  const unsigned short* xhh = xsh + (size_t)bh*Jc*Dc;
  const unsigned short* xmm = xsm + (size_t)bh*Jc*Dc;
  const unsigned short* xll = xsl + (size_t)bh*Jc*Dc;
  f32x4 oa[2][4];
  #pragma unroll
  for (int m = 0; m < 2; ++m)
    #pragma unroll
    for (int n = 0; n < 4; ++n) oa[m][n] = 0.f;

  for (int m = 0; m < Mc; ++m) {
    f32x4 acc[2][4];
    #pragma unroll
    for (int mm = 0; mm < 2; ++mm)
      #pragma unroll
      for (int nn = 0; nn < 4; ++nn) acc[mm][nn] = 0.f;
    #pragma unroll
    for (int kc = 0; kc < Dc; kc += 32) {
      int ko = kc + lg*8;
      bf16x8 ah[2], am2[2], al2[2], bhv[4], bmv[4], blv[4];
      #pragma unroll
      for (int mm = 0; mm < 2; ++mm) {
        ah[mm]  = *(const bf16x8*)&Ah[R0+16*mm+l16][ko];
        am2[mm] = *(const bf16x8*)&Am[R0+16*mm+l16][ko];
        al2[mm] = *(const bf16x8*)&Al[R0+16*mm+l16][ko];
      }
      #pragma unroll
      for (int nn = 0; nn < 4; ++nn) {
        size_t p = (size_t)(m*Fc + C0 + 16*nn + l16)*Dc + ko;
        bhv[nn] = *(const bf16x8*)(xhh + p);
        bmv[nn] = *(const bf16x8*)(xmm + p);
        blv[nn] = *(const bf16x8*)(xll + p);
      }
      #pragma unroll
      for (int mm = 0; mm < 2; ++mm)
        #pragma unroll
        for (int nn = 0; nn < 4; ++nn) {
          acc[mm][nn] = __builtin_amdgcn_mfma_f32_16x16x32_bf16(am2[mm], bmv[nn], acc[mm][nn], 0,0,0);
          acc[mm][nn] = __builtin_amdgcn_mfma_f32_16x16x32_bf16(ah[mm],  blv[nn], acc[mm][nn], 0,0,0);
          acc[mm][nn] = __builtin_amdgcn_mfma_f32_16x16x32_bf16(al2[mm], bhv[nn], acc[mm][nn], 0,0,0);
          acc[mm][nn] = __builtin_amdgcn_mfma_f32_16x16x32_bf16(ah[mm],  bmv[nn], acc[mm][nn], 0,0,0);
          acc[mm][nn] = __builtin_amdgcn_mfma_f32_16x16x32_bf16(am2[mm], bhv[nn], acc[mm][nn], 0,0,0);
          acc[mm][nn] = __builtin_amdgcn_mfma_f32_16x16x32_bf16(ah[mm],  bhv[nn], acc[mm][nn], 0,0,0);
        }
    }
    #pragma unroll
    for (int mm = 0; mm < 2; ++mm)
      #pragma unroll
      for (int nn = 0; nn < 4; ++nn) {
        int c = C0 + 16*nn + l16;
        float d2v = d2s[m][c], sg = sgs[m][c];
        #pragma unroll
        for (int r = 0; r < 4; ++r) {
          int row = R0 + 16*mm + 4*lg + r;
          oa[mm][nn][r] += sg * __expf(acc[mm][nn][r] - d1s[row] - d2v);
        }
      }
  }
  #pragma unroll
  for (int mm = 0; mm < 2; ++mm)
    #pragma unroll
    for (int nn = 0; nn < 4; ++nn) {
      int c = C0 + 16*nn + l16;
      #pragma unroll
      for (int r = 0; r < 4; ++r) {
        int row = R0 + 16*mm + 4*lg + r;
        AS[((size_t)bh*T2c + t0 + row)*Fc + c] = oa[mm][nn][r];
      }
    }
}

// ---------------- STAS build + normalize + K split planes + global colsum max ----------------
__global__ __launch_bounds__(256) void stas_kernel(
    const float* __restrict__ AS, const int* __restrict__ sketch,
    const float* __restrict__ sign,
    float* __restrict__ STASn, float* __restrict__ Dinv,
    unsigned short* __restrict__ Kh, unsigned short* __restrict__ Km,
    unsigned short* __restrict__ Kl,
    unsigned int* __restrict__ gmax) {
  extern __shared__ float stas[];   // [128][129]
  __shared__ int   Ssh[Jc];
  __shared__ float sgn[Jc];
  __shared__ float Dl[Fc];
  __shared__ float red[Fc];
  int bh = blockIdx.x;
  int b  = bh >> 3;
  int tid = threadIdx.x;
  for (int i = tid; i < Jc; i += 256) {
    Ssh[i] = sketch[b*Jc + i];
    sgn[i] = sign[b*Jc + i];
  }
  __syncthreads();
  for (int i = tid; i < Fc*Fc; i += 256) {
    int dd = i >> 7, e = i & 127;
    float vsum = 0.f;
    #pragma unroll
    for (int m = 0; m < Mc; ++m) {
      int t = Ssh[m*Fc + dd];
      vsum += sgn[m*Fc + dd] * AS[((size_t)bh*T2c + t)*Fc + e];
    }
    if (dd == e) vsum += 0.1f;
    stas[dd*129 + e] = vsum;
  }
  __syncthreads();
  if (tid < Fc) {
    float s = 0.f;
    for (int e = 0; e < Fc; ++e) s += stas[tid*129 + e];
    float di = 1.0f / sqrtf(s);
    Dl[tid] = di;
    Dinv[bh*Fc + tid] = di;
  }
  __syncthreads();
  for (int i = tid; i < Fc*Fc; i += 256) {
    int dd = i >> 7, e = i & 127;
    float vv = stas[dd*129 + e] * Dl[dd] * Dl[e];
    stas[dd*129 + e] = vv;
    STASn[(size_t)bh*Fc*Fc + i] = vv;
    unsigned short hb = f2bf_rne(vv); float r1 = vv - bf2f(hb);
    unsigned short mb = f2bf_rne(r1); float r2 = r1 - bf2f(mb);
    Kh[(size_t)bh*Fc*Fc + i] = hb;
    Km[(size_t)bh*Fc*Fc + i] = mb;
    Kl[(size_t)bh*Fc*Fc + i] = f2bf_rne(r2);
  }
  __syncthreads();
  if (tid < Fc) {
    float s = 0.f;
    for (int dd = 0; dd < Fc; ++dd) s += stas[dd*129 + tid];
    red[tid] = s;
  }
  __syncthreads();
  if (tid == 0) {
    float mx = 0.f;
    for (int e = 0; e < Fc; ++e) mx = fmaxf(mx, red[e]);
    atomicMax(gmax, __float_as_uint(mx));
  }
}

// ---------------- Newton-Schulz + fused ctx_raw (G = K^T (m^2 v)) ----------------
__device__ __forceinline__ unsigned aoff(int brow, int ke) {
  unsigned byte = ((unsigned)brow << 9) | ((unsigned)ke << 2);
  return byte ^ (((unsigned)(brow & 7)) << 4);
}
__device__ __forceinline__ unsigned boff(int brow, int ke) {
  unsigned byte = ((unsigned)brow << 8) | ((unsigned)ke << 1);
  return byte ^ (((unsigned)(brow & 7)) << 4);
}

__device__ __forceinline__ void split8(const f32x4& a, const f32x4& b,
                                       bf16x8& h, bf16x8& m, bf16x8& l) {
  float t[8] = {a[0],a[1],a[2],a[3],b[0],b[1],b[2],b[3]};
  #pragma unroll
  for (int j = 0; j < 8; ++j) {
    float x = t[j];
    unsigned short hb = f2bf_rne(x);
    float r1 = x - bf2f(hb);
    unsigned short mb = f2bf_rne(r1);
    float r2 = r1 - bf2f(mb);
    h[j] = (short)hb; m[j] = (short)mb; l[j] = (short)f2bf_rne(r2);
  }
}

__device__ __forceinline__ void ld_splitA(const char* Af, int brow, int ko,
                                          bf16x8& h, bf16x8& m, bf16x8& l) {
  f32x4 a = *(const f32x4*)(Af + aoff(brow, ko));
  f32x4 b = *(const f32x4*)(Af + aoff(brow, ko + 4));
  split8(a, b, h, m, l);
}

__device__ __forceinline__ void mm6(const bf16x8 ah[2], const bf16x8 am[2], const bf16x8 al[2],
                                    const bf16x8 bh[4], const bf16x8 bm[4], const bf16x8 bl[4],
                                    f32x4 acc[2][4]) {
  #pragma unroll
  for (int m = 0; m < 2; ++m)
    #pragma unroll
    for (int n = 0; n < 4; ++n) {
      acc[m][n] = __builtin_amdgcn_mfma_f32_16x16x32_bf16(am[m], bm[n], acc[m][n], 0,0,0);
      acc[m][n] = __builtin_amdgcn_mfma_f32_16x16x32_bf16(ah[m], bl[n], acc[m][n], 0,0,0);
      acc[m][n] = __builtin_amdgcn_mfma_f32_16x16x32_bf16(al[m], bh[n], acc[m][n], 0,0,0);
      acc[m][n] = __builtin_amdgcn_mfma_f32_16x16x32_bf16(ah[m], bm[n], acc[m][n], 0,0,0);
      acc[m][n] = __builtin_amdgcn_mfma_f32_16x16x32_bf16(am[m], bh[n], acc[m][n], 0,0,0);
      acc[m][n] = __builtin_amdgcn_mfma_f32_16x16x32_bf16(ah[m], bh[n], acc[m][n], 0,0,0);
    }
}

__device__ __forceinline__ void mm_p1(
    const unsigned short* __restrict__ kh, const unsigned short* __restrict__ km,
    const unsigned short* __restrict__ kl, const char* Af,
    int R0, int C0, int l16, int lg, f32x4 acc[2][4]) {
  #pragma unroll 1
  for (int kc = 0; kc < Fc; kc += 32) {
    int ko = kc + lg*8;
    bf16x8 ah[2], am[2], al[2], bh[4], bm[4], bl[4];
    #pragma unroll
    for (int m = 0; m < 2; ++m) {
      size_t p = (size_t)(R0+16*m+l16)*Fc + ko;
      ah[m] = *(const bf16x8*)(kh + p);
      am[m] = *(const bf16x8*)(km + p);
      al[m] = *(const bf16x8*)(kl + p);
    }
    #pragma unroll
    for (int n = 0; n < 4; ++n)
      ld_splitA(Af, C0+16*n+l16, ko, bh[n], bm[n], bl[n]);
    mm6(ah, am, al, bh, bm, bl, acc);
  }
}

__device__ __forceinline__ void mm_ldsB(const char* Af,
    const char* Zh, const char* Zm, const char* Zl,
    int R0, int C0, int l16, int lg, f32x4 acc[2][4]) {
  #pragma unroll 1
  for (int kc = 0; kc < Fc; kc += 32) {
    int ko = kc + lg*8;
    bf16x8 ah[2], am[2], al[2], bh[4], bm[4], bl[4];
    #pragma unroll
    for (int m = 0; m < 2; ++m)
      ld_splitA(Af, R0+16*m+l16, ko, ah[m], am[m], al[m]);
    #pragma unroll
    for (int n = 0; n < 4; ++n) {
      unsigned off = boff(C0+16*n+l16, ko);
      bh[n] = *(const bf16x8*)(Zh + off);
      bm[n] = *(const bf16x8*)(Zm + off);
      bl[n] = *(const bf16x8*)(Zl + off);
    }
    mm6(ah, am, al, bh, bm, bl, acc);
  }
}

__device__ __forceinline__ void wbA(char* Af, int col, int row0, f32x4 v) {
  *(f32x4*)(Af + aoff(col, row0)) = v;
}
__device__ __forceinline__ void wbZ(char* Zh, char* Zm, char* Zl,
                                    int col, int row0, f32x4 v) {
  u16x4 hv, mv, lv;
  #pragma unroll
  for (int r = 0; r < 4; ++r) {
    unsigned short hb = f2bf_rne(v[r]); float r1 = v[r] - bf2f(hb);
    unsigned short mb = f2bf_rne(r1);   float r2 = r1 - bf2f(mb);
    hv[r] = hb; mv[r] = mb; lv[r] = f2bf_rne(r2);
  }
  unsigned off = boff(col, row0);
  *(u16x4*)(Zh + off) = hv;
  *(u16x4*)(Zm + off) = mv;
  *(u16x4*)(Zl + off) = lv;
}

__global__ __launch_bounds__(512) void newton_ctx_kernel(
    const float* __restrict__ STASn,
    const unsigned short* __restrict__ KhG, const unsigned short* __restrict__ KmG,
    const unsigned short* __restrict__ KlG,
    const float* __restrict__ gmaxf, float* __restrict__ Vout,
    const float* __restrict__ ASg, const float* __restrict__ vg,
    const float* __restrict__ maskg, float* __restrict__ Gpart) {
  extern __shared__ char smc[];
  int tid  = threadIdx.x;

  if (blockIdx.x < BHc) {
    // ================= Newton path (verbatim round 6) =================
    char* Zh = smc;
    char* Zm = smc + 32768;
    char* Zl = smc + 65536;
    char* Af = smc + 98304;
    int bh = blockIdx.x;
    const float* Kp = STASn + (size_t)bh*Fc*Fc;
    const unsigned short* kh = KhG + (size_t)bh*Fc*Fc;
    const unsigned short* km = KmG + (size_t)bh*Fc*Fc;
    const unsigned short* kl = KlG + (size_t)bh*Fc*Fc;
    float ginv = 1.0f / gmaxf[0];
    int lane = tid & 63;
    int wid  = tid >> 6;
    int wr = wid >> 1, wc = wid & 1;
    int l16 = lane & 15, lg = lane >> 4;
    int R0 = wr*32, C0 = wc*64;
    int drow0 = lg*4;

    f32x4 vreg[2][4];
    #pragma unroll
    for (int m = 0; m < 2; ++m)
      #pragma unroll
      for (int n = 0; n < 4; ++n) {
        int col = C0 + 16*n + l16;
        #pragma unroll
        for (int r = 0; r < 4; ++r)
          vreg[m][n][r] = Kp[(size_t)(R0 + 16*m + drow0 + r)*Fc + col] * ginv;
        wbA(Af, col, R0 + 16*m + drow0, vreg[m][n]);
      }
    __syncthreads();

    f32x4 fin[2][4];
    for (int it = 0; it < 6; ++it) {
      f32x4 acc[2][4];
      // P1: Z = K @ V
      #pragma unroll
      for (int m = 0; m < 2; ++m) for (int n = 0; n < 4; ++n) acc[m][n] = 0.f;
      mm_p1(kh, km, kl, Af, R0, C0, l16, lg, acc);
      #pragma unroll
      for (int m = 0; m < 2; ++m)
        #pragma unroll
        for (int n = 0; n < 4; ++n)
          wbZ(Zh, Zm, Zl, C0 + 16*n + l16, R0 + 16*m + drow0, acc[m][n]);
      __syncthreads();

      // P2: W1 = V @ Z ; fin = 13V - 15W1
      #pragma unroll
      for (int m = 0; m < 2; ++m) for (int n = 0; n < 4; ++n) acc[m][n] = 0.f;
      mm_ldsB(Af, Zh, Zm, Zl, R0, C0, l16, lg, acc);
      #pragma unroll
      for (int m = 0; m < 2; ++m)
        #pragma unroll
        for (int n = 0; n < 4; ++n)
          fin[m][n] = 13.f*vreg[m][n] - 15.f*acc[m][n];
      __syncthreads();
      #pragma unroll
      for (int m = 0; m < 2; ++m)
        #pragma unroll
        for (int n = 0; n < 4; ++n)
          wbA(Af, C0 + 16*n + l16, R0 + 16*m + drow0, acc[m][n]);
      __syncthreads();

      // P3: W2 = W1 @ Z ; fin += 7W2
      #pragma unroll
      for (int m = 0; m < 2; ++m) for (int n = 0; n < 4; ++n) acc[m][n] = 0.f;
      mm_ldsB(Af, Zh, Zm, Zl, R0, C0, l16, lg, acc);
      #pragma unroll
      for (int m = 0; m < 2; ++m)
        #pragma unroll
        for (int n = 0; n < 4; ++n)
          fin[m][n] += 7.f*acc[m][n];
      __syncthreads();
      #pragma unroll
      for (int m = 0; m < 2; ++m)
        #pragma unroll
        for (int n = 0; n < 4; ++n)
          wbA(Af, C0 + 16*n + l16, R0 + 16*m + drow0, acc[m][n]);
      __syncthreads();

      // P4: W3 = W2 @ Z ; V <- 0.25(fin - W3)
      #pragma unroll
      for (int m = 0; m < 2; ++m) for (int n = 0; n < 4; ++n) acc[m][n] = 0.f;
      mm_ldsB(Af, Zh, Zm, Zl, R0, C0, l16, lg, acc);
      #pragma unroll
      for (int m = 0; m < 2; ++m)
        #pragma unroll
        for (int n = 0; n < 4; ++n) {
          fin[m][n] = 0.25f*(fin[m][n] - acc[m][n]);
          vreg[m][n] = fin[m][n];
        }
      __syncthreads();
      #pragma unroll
      for (int m = 0; m < 2; ++m)
        #pragma unroll
        for (int n = 0; n < 4; ++n)
          wbA(Af, C0 + 16*n + l16, R0 + 16*m + drow0, fin[m][n]);
      __syncthreads();
    }

    float* Vo = Vout + (size_t)bh*Fc*Fc;
    #pragma unroll
    for (int m = 0; m < 2; ++m)
      #pragma unroll
      for (int n = 0; n < 4; ++n) {
        int col = C0 + 16*n + l16;
        #pragma unroll
        for (int r = 0; r < 4; ++r)
          Vo[(size_t)(R0 + 16*m + drow0 + r)*Fc + col] = vreg[m][n][r];
      }
  } else {
    // ================= ctx_raw path: G_part = K^T (m^2 v) over a 512-row chunk ====
    float* Ksh = (float*)smc;              // [64][128]
    float* vsh = (float*)(smc + 32768);    // [64][64]
    int id = blockIdx.x - BHc;             // 0..127
    int cbh = id >> 2, chunk = id & 3;
    int cb = cbh >> 3;
    int t0 = chunk * 512;
    int f = tid & 127, g = tid >> 7;       // g in 0..3
    float acc[16];
    #pragma unroll
    for (int j = 0; j < 16; ++j) acc[j] = 0.f;
    for (int sub = 0; sub < 8; ++sub) {
      __syncthreads();
      int ts = t0 + sub*64;
      for (int i = tid; i < 64*32; i += 512) {
        int r = i >> 5, c4 = i & 31;
        *(float4*)&Ksh[r*128 + c4*4] =
            *(const float4*)(ASg + ((size_t)cbh*T2c + Nc + ts + r)*Fc + c4*4);
      }
      for (int i = tid; i < 64*16; i += 512) {
        int r = i >> 4, c4 = i & 15;
        float mk = maskg[cb*Nc + ts + r];
        float m2 = mk*mk;
        float4 x = *(const float4*)(vg + ((size_t)cbh*Nc + ts + r)*Dc + c4*4);
        x.x*=m2; x.y*=m2; x.z*=m2; x.w*=m2;
        *(float4*)&vsh[r*64 + c4*4] = x;
      }
      __syncthreads();
      #pragma unroll 2
      for (int tl = 0; tl < 64; ++tl) {
        float kf = Ksh[tl*128 + f];
        #pragma unroll
        for (int j4 = 0; j4 < 4; ++j4) {
          float4 vv = *(const float4*)&vsh[tl*64 + g*16 + j4*4];
          acc[j4*4+0] += kf*vv.x; acc[j4*4+1] += kf*vv.y;
          acc[j4*4+2] += kf*vv.z; acc[j4*4+3] += kf*vv.w;
        }
      }
    }
    float* gp = Gpart + ((((size_t)cbh*4 + chunk)*128 + f)*64 + g*16);
    #pragma unroll
    for (int j4 = 0; j4 < 4; ++j4)
      *(float4*)(gp + j4*4) = *(const float4*)&acc[j4*4];
  }
}

// ---------------- ctx_fix: context[f][ee] = Dinv[f] * sum_e STASinv[e][f]*Dinv[e]*G[e][ee] ----
__global__ __launch_bounds__(256) void ctx_fix_kernel(
    const float* __restrict__ Gpart, const float* __restrict__ Vinv,
    const float* __restrict__ Dinv, float* __restrict__ ctxo) {
  __shared__ float DG[128*64];
  __shared__ float Dl[128];
  int bh = blockIdx.x;
  int tid = threadIdx.x;
  if (tid < 128) Dl[tid] = Dinv[bh*Fc + tid];
  __syncthreads();
  for (int i = tid; i < 2048; i += 256) {     // float4 granules over 128x64
    int e = i >> 4, c4 = i & 15;
    const float* g0 = Gpart + ((((size_t)bh*4)*128 + e)*64 + c4*4);
    float4 s0 = *(const float4*)(g0);
    float4 s1 = *(const float4*)(g0 + 8192);
    float4 s2 = *(const float4*)(g0 + 16384);
    float4 s3 = *(const float4*)(g0 + 24576);
    float de = Dl[e];
    float4 o;
    o.x = (s0.x+s1.x+s2.x+s3.x)*de;
    o.y = (s0.y+s1.y+s2.y+s3.y)*de;
    o.z = (s0.z+s1.z+s2.z+s3.z)*de;
    o.w = (s0.w+s1.w+s2.w+s3.w)*de;
    *(float4*)&DG[e*64 + c4*4] = o;
  }
  __syncthreads();
  int f = tid & 127, half = tid >> 7;
  float acc[32];
  #pragma unroll
  for (int j = 0; j < 32; ++j) acc[j] = 0.f;
  for (int e = 0; e < 128; ++e) {
    float s = Vinv[(size_t)bh*Fc*Fc + (size_t)e*Fc + f];
    #pragma unroll
    for (int j4 = 0; j4 < 8; ++j4) {
      float4 dg = *(const float4*)&DG[e*64 + half*32 + j4*4];
      acc[j4*4+0] += s*dg.x; acc[j4*4+1] += s*dg.y;
      acc[j4*4+2] += s*dg.z; acc[j4*4+3] += s*dg.w;
    }
  }
  float df = Dl[f];
  float* op = ctxo + (size_t)bh*Fc*Dc + f*Dc + half*32;
  #pragma unroll
  for (int j4 = 0; j4 < 8; ++j4) {
    float4 o;
    o.x = acc[j4*4+0]*df; o.y = acc[j4*4+1]*df;
    o.z = acc[j4*4+2]*df; o.w = acc[j4*4+3]*df;
    *(float4*)(op + j4*4) = o;
  }
}

// ---------------- out = Q @ context ----------------
__global__ __launch_bounds__(256) void out_kernel(
    const float* __restrict__ AS, const float* __restrict__ ctx,
    float* __restrict__ out) {
  extern __shared__ float smo[];
  float* Asq = smo;            // [64][132]
  float* Cs  = smo + 64*132;   // [128][64]
  int bh = blockIdx.y;
  int row0 = blockIdx.x * 64;
  int tid = threadIdx.x;
  int tr = tid >> 4, tc = tid & 15;
  for (int i = tid; i < 64*32; i += 256) {
    int r = i >> 5, kq = i & 31;
    *(float4*)&Asq[r*132 + kq*4] =
        *(const float4*)(AS + ((size_t)bh*T2c + row0 + r)*Fc + kq*4);
  }
  for (int i = tid; i < 128*16; i += 256) {
    int r = i >> 4, kq = i & 15;
    *(float4*)&Cs[r*64 + kq*4] =
        *(const float4*)(ctx + (size_t)bh*Fc*Dc + r*Dc + kq*4);
  }
  __syncthreads();
  float acc[4][4] = {};
  #pragma unroll 2
  for (int kk = 0; kk < Fc; ++kk) {
    float4 bv = *(const float4*)&Cs[kk*64 + tc*4];
    float a0 = Asq[(tr*4+0)*132 + kk];
    float a1 = Asq[(tr*4+1)*132 + kk];
    float a2 = Asq[(tr*4+2)*132 + kk];
    float a3 = Asq[(tr*4+3)*132 + kk];
    acc[0][0] += a0*bv.x; acc[0][1] += a0*bv.y; acc[0][2] += a0*bv.z; acc[0][3] += a0*bv.w;
    acc[1][0] += a1*bv.x; acc[1][1] += a1*bv.y; acc[1][2] += a1*bv.z; acc[1][3] += a1*bv.w;
    acc[2][0] += a2*bv.x; acc[2][1] += a2*bv.y; acc[2][2] += a2*bv.z; acc[2][3] += a2*bv.w;
    acc[3][0] += a3*bv.x; acc[3][1] += a3*bv.y; acc[3][2] += a3*bv.z; acc[3][3] += a3*bv.w;
  }
  #pragma unroll
  for (int i = 0; i < 4; ++i) {
    float4 o;
    o.x = acc[i][0]; o.y = acc[i][1]; o.z = acc[i][2]; o.w = acc[i][3];
    *(float4*)(out + ((size_t)bh*Nc + row0 + tr*4 + i)*Dc + tc*4) = o;
  }
}

extern "C" void kernel_launch(void* const* d_in, const int* in_sizes, int n_in,
                              void* d_out, int out_size, void* d_ws, size_t ws_size,
                              hipStream_t stream) {
  const float* q    = (const float*)d_in[0];
  const float* k    = (const float*)d_in[1];
  const float* v    = (const float*)d_in[2];
  const float* mask = (const float*)d_in[3];
  const float* sign = (const float*)d_in[4];
  const int*   sketch = (const int*)d_in[5];
  float* out = (float*)d_out;
  float* ws  = (float*)d_ws;

  unsigned short* xsh = (unsigned short*)(ws + OFF_XSH);
  unsigned short* xsm = (unsigned short*)(ws + OFF_XSM);
  unsigned short* xsl = (unsigned short*)(ws + OFF_XSL);
  unsigned short* kh  = (unsigned short*)(ws + OFF_KH);
  unsigned short* km  = (unsigned short*)(ws + OFF_KM);
  unsigned short* kl  = (unsigned short*)(ws + OFF_KL);

  hipMemsetAsync(ws + OFF_GMAX, 0, sizeof(float), stream);

  diag1_kernel<<<BHc*T2c*16/256, 256, 0, stream>>>(q, k, mask, ws + OFF_DIAG1);
  gather_kernel<<<BHc*Jc*16/256, 256, 0, stream>>>(q, k, mask, sketch, ws + OFF_DIAG1,
                                                   xsh, xsm, xsl, ws + OFF_DIAG2);
  as_mfma_kernel<<<dim3(T2c/64, BHc), 256, 0, stream>>>(q, k, mask, xsh, xsm, xsl,
      ws + OFF_DIAG1, ws + OFF_DIAG2, sign, ws + OFF_AS);
  stas_kernel<<<BHc, 256, 128*129*sizeof(float), stream>>>(ws + OFF_AS, sketch, sign,
      ws + OFF_STASN, ws + OFF_DINV, kh, km, kl, (unsigned int*)(ws + OFF_GMAX));
  // fused: 32 newton blocks + 128 ctx blocks (1 block/CU at 160KB LDS)
  newton_ctx_kernel<<<BHc + 128, 512, 163840, stream>>>(ws + OFF_STASN, kh, km, kl,
      ws + OFF_GMAX, ws + OFF_VBUF, ws + OFF_AS, v, mask, ws + OFF_GPART);
  ctx_fix_kernel<<<BHc, 256, 0, stream>>>(ws + OFF_GPART, ws + OFF_VBUF,
      ws + OFF_DINV, ws + OFF_CTX);
  out_kernel<<<dim3(Nc/64, BHc), 256, (64*132 + 128*64)*sizeof(float), stream>>>(
      ws + OFF_AS, ws + OFF_CTX, out);
}

// Round 8
// 359.576 us; speedup vs baseline: 2.1450x; 1.0551x over previous
//
#include <hip/hip_runtime.h>

constexpr int Bc = 4, Hc = 8, Nc = 2048, Dc = 64, Fc = 128, Mc = 4;
constexpr int BHc = Bc*Hc;        // 32
constexpr int T2c = 2*Nc;         // 4096
constexpr int Jc  = Mc*Fc;        // 512
constexpr float DNORM = 0.4204482076268573f;   // 32^-0.25

// workspace offsets (in floats)
constexpr size_t OFF_AS    = 0;                                 // 16777216
constexpr size_t OFF_XSH   = OFF_AS    + (size_t)BHc*T2c*Fc;    // xs h-plane (ushort)
constexpr size_t OFF_XSM   = OFF_XSH   + (size_t)BHc*Jc*Dc/2;   // xs m-plane
constexpr size_t OFF_XSL   = OFF_XSM   + (size_t)BHc*Jc*Dc/2;   // xs l-plane
constexpr size_t OFF_DIAG1 = OFF_XSL   + (size_t)BHc*Jc*Dc/2;
constexpr size_t OFF_DIAG2 = OFF_DIAG1 + (size_t)BHc*T2c;
constexpr size_t OFF_STASN = OFF_DIAG2 + (size_t)BHc*Jc;
constexpr size_t OFF_VBUF  = OFF_STASN + (size_t)BHc*Fc*Fc;
constexpr size_t OFF_DINV  = OFF_VBUF  + (size_t)BHc*Fc*Fc;
constexpr size_t OFF_GMAX  = OFF_DINV  + (size_t)BHc*Fc;
constexpr size_t OFF_CTX   = OFF_GMAX  + 64;
constexpr size_t OFF_KH    = OFF_CTX   + (size_t)BHc*Fc*Dc;     // K h-plane (ushort)
constexpr size_t OFF_KM    = OFF_KH    + (size_t)BHc*Fc*Fc/2;
constexpr size_t OFF_KL    = OFF_KM    + (size_t)BHc*Fc*Fc/2;
// reuse of xs-plane region (dead after as_mfma):
constexpr size_t OFF_GPART = OFF_XSH;                           // [BHc][4][128][64] floats
constexpr size_t OFF_ZSC   = OFF_GPART + (size_t)BHc*4*128*64;  // Zl scratch: BHc*16384 ushort
// OFF_ZSC + 262144 floats = OFF_XSH + 1,310,720 < OFF_XSH + 1,572,864 (region end)

typedef __attribute__((ext_vector_type(8))) short bf16x8;
typedef __attribute__((ext_vector_type(4))) float f32x4;
typedef __attribute__((ext_vector_type(4))) unsigned short u16x4;

__device__ __forceinline__ unsigned short f2bf_rne(float x) {
  unsigned int u = __float_as_uint(x);
  u += 0x7fff + ((u >> 16) & 1);
  return (unsigned short)(u >> 16);
}
__device__ __forceinline__ float bf2f(unsigned short h) {
  return __uint_as_float(((unsigned int)h) << 16);
}

// ---------------- diag1 ----------------
__global__ __launch_bounds__(256) void diag1_kernel(
    const float* __restrict__ q, const float* __restrict__ k,
    const float* __restrict__ mask, float* __restrict__ diag1) {
  int gid = blockIdx.x*256 + threadIdx.x;
  int kq  = gid & 15;
  int row = gid >> 4;
  int t   = row & (T2c - 1);
  int bh  = row >> 12;
  int b   = bh >> 3;
  int tn  = (t < Nc) ? t : t - Nc;
  const float* src = ((t < Nc) ? q : k) + ((size_t)bh*Nc + tn)*Dc;
  float sc = DNORM * mask[b*Nc + tn];
  float4 x = *(const float4*)(src + kq*4);
  float s = x.x*x.x + x.y*x.y + x.z*x.z + x.w*x.w;
  s += __shfl_xor(s, 1);
  s += __shfl_xor(s, 2);
  s += __shfl_xor(s, 4);
  s += __shfl_xor(s, 8);
  if (kq == 0) diag1[row] = 0.5f * sc * sc * s;
}

// ---------------- gather -> pre-split bf16 h/m/l planes + diag2 ----------------
__global__ __launch_bounds__(256) void gather_kernel(
    const float* __restrict__ q, const float* __restrict__ k,
    const float* __restrict__ mask, const int* __restrict__ sketch,
    const float* __restrict__ diag1,
    unsigned short* __restrict__ xsh, unsigned short* __restrict__ xsm,
    unsigned short* __restrict__ xsl, float* __restrict__ diag2) {
  int gid = blockIdx.x*256 + threadIdx.x;
  int kq  = gid & 15;
  int idx = gid >> 4;
  int j   = idx & (Jc - 1);
  int bh  = idx >> 9;
  int b   = bh >> 3;
  int t   = sketch[b*Jc + j];
  int tn  = (t < Nc) ? t : t - Nc;
  const float* src = ((t < Nc) ? q : k) + ((size_t)bh*Nc + tn)*Dc;
  float sc = DNORM * mask[b*Nc + tn];
  float4 x = *(const float4*)(src + kq*4);
  float xv[4] = {x.x*sc, x.y*sc, x.z*sc, x.w*sc};
  u16x4 hh, mm_, ll;
  #pragma unroll
  for (int jj = 0; jj < 4; ++jj) {
    unsigned short h = f2bf_rne(xv[jj]);
    float r1 = xv[jj] - bf2f(h);
    unsigned short m = f2bf_rne(r1);
    float r2 = r1 - bf2f(m);
    hh[jj] = h; mm_[jj] = m; ll[jj] = f2bf_rne(r2);
  }
  *(u16x4*)(xsh + (size_t)idx*Dc + kq*4) = hh;
  *(u16x4*)(xsm + (size_t)idx*Dc + kq*4) = mm_;
  *(u16x4*)(xsl + (size_t)idx*Dc + kq*4) = ll;
  if (kq == 0) diag2[idx] = diag1[bh*T2c + t];
}

// ---------------- AS GEMM via MFMA, 3-way rne split ----------------
__global__ __launch_bounds__(256) void as_mfma_kernel(
    const float* __restrict__ q, const float* __restrict__ k,
    const float* __restrict__ mask,
    const unsigned short* __restrict__ xsh, const unsigned short* __restrict__ xsm,
    const unsigned short* __restrict__ xsl,
    const float* __restrict__ diag1, const float* __restrict__ diag2,
    const float* __restrict__ sign, float* __restrict__ AS) {
  __shared__ __align__(16) unsigned short Ah[64][72];
  __shared__ __align__(16) unsigned short Am[64][72];
  __shared__ __align__(16) unsigned short Al[64][72];
  __shared__ float d1s[64];
  __shared__ float d2s[4][128];
  __shared__ float sgs[4][128];
  int bh = blockIdx.y, b = bh >> 3;
  int t0 = blockIdx.x * 64;
  int tid = threadIdx.x;
  int lane = tid & 63, wid = tid >> 6;
  int wr = wid >> 1, wc = wid & 1;
  int l16 = lane & 15, lg = lane >> 4;
  int R0 = wr*32, C0 = wc*64;

  for (int i = tid; i < 64*16; i += 256) {
    int r = i >> 4, kq = i & 15;
    int t = t0 + r;
    int tn = (t < Nc) ? t : t - Nc;
    const float* src = ((t < Nc) ? q : k) + ((size_t)bh*Nc + tn)*Dc + kq*4;
    float sc = DNORM * mask[b*Nc + tn];
    float4 x = *(const float4*)src;
    float xv[4] = {x.x*sc, x.y*sc, x.z*sc, x.w*sc};
    u16x4 hv, mv, lv;
    #pragma unroll
    for (int jj = 0; jj < 4; ++jj) {
      unsigned short h = f2bf_rne(xv[jj]);
      float r1 = xv[jj] - bf2f(h);
      unsigned short m = f2bf_rne(r1);
      float r2 = r1 - bf2f(m);
      hv[jj] = h; mv[jj] = m; lv[jj] = f2bf_rne(r2);
    }
    *(u16x4*)&Ah[r][kq*4] = hv;
    *(u16x4*)&Am[r][kq*4] = mv;
    *(u16x4*)&Al[r][kq*4] = lv;
  }
  if (tid < 64) d1s[tid] = diag1[bh*T2c + t0 + tid];
  for (int i = tid; i < 512; i += 256) {
    d2s[i>>7][i&127] = diag2[bh*Jc + i];
    sgs[i>>7][i&127] = sign[b*Jc + i];
  }
  __syncthreads();

  const unsigned short* xhh = xsh + (size_t)bh*Jc*Dc;
  const unsigned short* xmm = xsm + (size_t)bh*Jc*Dc;
  const unsigned short* xll = xsl + (size_t)bh*Jc*Dc;
  f32x4 oa[2][4];
  #pragma unroll
  for (int m = 0; m < 2; ++m)
    #pragma unroll
    for (int n = 0; n < 4; ++n) oa[m][n] = 0.f;

  for (int m = 0; m < Mc; ++m) {
    f32x4 acc[2][4];
    #pragma unroll
    for (int mm = 0; mm < 2; ++mm)
      #pragma unroll
      for (int nn = 0; nn < 4; ++nn) acc[mm][nn] = 0.f;
    #pragma unroll
    for (int kc = 0; kc < Dc; kc += 32) {
      int ko = kc + lg*8;
      bf16x8 ah[2], am2[2], al2[2], bhv[4], bmv[4], blv[4];
      #pragma unroll
      for (int mm = 0; mm < 2; ++mm) {
        ah[mm]  = *(const bf16x8*)&Ah[R0+16*mm+l16][ko];
        am2[mm] = *(const bf16x8*)&Am[R0+16*mm+l16][ko];
        al2[mm] = *(const bf16x8*)&Al[R0+16*mm+l16][ko];
      }
      #pragma unroll
      for (int nn = 0; nn < 4; ++nn) {
        size_t p = (size_t)(m*Fc + C0 + 16*nn + l16)*Dc + ko;
        bhv[nn] = *(const bf16x8*)(xhh + p);
        bmv[nn] = *(const bf16x8*)(xmm + p);
        blv[nn] = *(const bf16x8*)(xll + p);
      }
      #pragma unroll
      for (int mm = 0; mm < 2; ++mm)
        #pragma unroll
        for (int nn = 0; nn < 4; ++nn) {
          acc[mm][nn] = __builtin_amdgcn_mfma_f32_16x16x32_bf16(am2[mm], bmv[nn], acc[mm][nn], 0,0,0);
          acc[mm][nn] = __builtin_amdgcn_mfma_f32_16x16x32_bf16(ah[mm],  blv[nn], acc[mm][nn], 0,0,0);
          acc[mm][nn] = __builtin_amdgcn_mfma_f32_16x16x32_bf16(al2[mm], bhv[nn], acc[mm][nn], 0,0,0);
          acc[mm][nn] = __builtin_amdgcn_mfma_f32_16x16x32_bf16(ah[mm],  bmv[nn], acc[mm][nn], 0,0,0);
          acc[mm][nn] = __builtin_amdgcn_mfma_f32_16x16x32_bf16(am2[mm], bhv[nn], acc[mm][nn], 0,0,0);
          acc[mm][nn] = __builtin_amdgcn_mfma_f32_16x16x32_bf16(ah[mm],  bhv[nn], acc[mm][nn], 0,0,0);
        }
    }
    #pragma unroll
    for (int mm = 0; mm < 2; ++mm)
      #pragma unroll
      for (int nn = 0; nn < 4; ++nn) {
        int c = C0 + 16*nn + l16;
        float d2v = d2s[m][c], sg = sgs[m][c];
        #pragma unroll
        for (int r = 0; r < 4; ++r) {
          int row = R0 + 16*mm + 4*lg + r;
          oa[mm][nn][r] += sg * __expf(acc[mm][nn][r] - d1s[row] - d2v);
        }
      }
  }
  #pragma unroll
  for (int mm = 0; mm < 2; ++mm)
    #pragma unroll
    for (int nn = 0; nn < 4; ++nn) {
      int c = C0 + 16*nn + l16;
      #pragma unroll
      for (int r = 0; r < 4; ++r) {
        int row = R0 + 16*mm + 4*lg + r;
        AS[((size_t)bh*T2c + t0 + row)*Fc + c] = oa[mm][nn][r];
      }
    }
}

// ---------------- STAS build + normalize + K split planes + global colsum max ----------------
__global__ __launch_bounds__(256) void stas_kernel(
    const float* __restrict__ AS, const int* __restrict__ sketch,
    const float* __restrict__ sign,
    float* __restrict__ STASn, float* __restrict__ Dinv,
    unsigned short* __restrict__ Kh, unsigned short* __restrict__ Km,
    unsigned short* __restrict__ Kl,
    unsigned int* __restrict__ gmax) {
  extern __shared__ float stas[];   // [128][129]
  __shared__ int   Ssh[Jc];
  __shared__ float sgn[Jc];
  __shared__ float Dl[Fc];
  __shared__ float red[Fc];
  int bh = blockIdx.x;
  int b  = bh >> 3;
  int tid = threadIdx.x;
  for (int i = tid; i < Jc; i += 256) {
    Ssh[i] = sketch[b*Jc + i];
    sgn[i] = sign[b*Jc + i];
  }
  __syncthreads();
  for (int i = tid; i < Fc*Fc; i += 256) {
    int dd = i >> 7, e = i & 127;
    float vsum = 0.f;
    #pragma unroll
    for (int m = 0; m < Mc; ++m) {
      int t = Ssh[m*Fc + dd];
      vsum += sgn[m*Fc + dd] * AS[((size_t)bh*T2c + t)*Fc + e];
    }
    if (dd == e) vsum += 0.1f;
    stas[dd*129 + e] = vsum;
  }
  __syncthreads();
  if (tid < Fc) {
    float s = 0.f;
    for (int e = 0; e < Fc; ++e) s += stas[tid*129 + e];
    float di = 1.0f / sqrtf(s);
    Dl[tid] = di;
    Dinv[bh*Fc + tid] = di;
  }
  __syncthreads();
  for (int i = tid; i < Fc*Fc; i += 256) {
    int dd = i >> 7, e = i & 127;
    float vv = stas[dd*129 + e] * Dl[dd] * Dl[e];
    stas[dd*129 + e] = vv;
    STASn[(size_t)bh*Fc*Fc + i] = vv;
    unsigned short hb = f2bf_rne(vv); float r1 = vv - bf2f(hb);
    unsigned short mb = f2bf_rne(r1); float r2 = r1 - bf2f(mb);
    Kh[(size_t)bh*Fc*Fc + i] = hb;
    Km[(size_t)bh*Fc*Fc + i] = mb;
    Kl[(size_t)bh*Fc*Fc + i] = f2bf_rne(r2);
  }
  __syncthreads();
  if (tid < Fc) {
    float s = 0.f;
    for (int dd = 0; dd < Fc; ++dd) s += stas[dd*129 + tid];
    red[tid] = s;
  }
  __syncthreads();
  if (tid == 0) {
    float mx = 0.f;
    for (int e = 0; e < Fc; ++e) mx = fmaxf(mx, red[e]);
    atomicMax(gmax, __float_as_uint(mx));
  }
}

// ---------------- Newton-Schulz (5-plane LDS, Zl -> L2 scratch) + fused ctx_raw ----------------
// All operands fully pre-split at write time. LDS: Ah/Am/Al (V,W1,W2 planes, transposed
// convention buf[col][row]=split(M[row][col])) + Zh/Zm; Zl in global scratch (L2).
// Values are bit-identical to round 7 (same split8 of the same fp32, moved to write side).
__device__ __forceinline__ unsigned boff(int brow, int ke) {
  unsigned byte = ((unsigned)brow << 8) | ((unsigned)ke << 1);
  return byte ^ (((unsigned)(brow & 7)) << 4);
}

__device__ __forceinline__ void mm6(const bf16x8 ah[2], const bf16x8 am[2], const bf16x8 al[2],
                                    const bf16x8 bh[4], const bf16x8 bm[4], const bf16x8 bl[4],
                                    f32x4 acc[2][4]) {
  #pragma unroll
  for (int m = 0; m < 2; ++m)
    #pragma unroll
    for (int n = 0; n < 4; ++n) {
      acc[m][n] = __builtin_amdgcn_mfma_f32_16x16x32_bf16(am[m], bm[n], acc[m][n], 0,0,0);
      acc[m][n] = __builtin_amdgcn_mfma_f32_16x16x32_bf16(ah[m], bl[n], acc[m][n], 0,0,0);
      acc[m][n] = __builtin_amdgcn_mfma_f32_16x16x32_bf16(al[m], bh[n], acc[m][n], 0,0,0);
      acc[m][n] = __builtin_amdgcn_mfma_f32_16x16x32_bf16(ah[m], bm[n], acc[m][n], 0,0,0);
      acc[m][n] = __builtin_amdgcn_mfma_f32_16x16x32_bf16(am[m], bh[n], acc[m][n], 0,0,0);
      acc[m][n] = __builtin_amdgcn_mfma_f32_16x16x32_bf16(ah[m], bh[n], acc[m][n], 0,0,0);
    }
}

__device__ __forceinline__ void ld3(const char* Ph, const char* Pm, const char* Pl,
                                    int brow, int ko, bf16x8& h, bf16x8& m, bf16x8& l) {
  unsigned off = boff(brow, ko);
  h = *(const bf16x8*)(Ph + off);
  m = *(const bf16x8*)(Pm + off);
  l = *(const bf16x8*)(Pl + off);
}

// P1: Z = K @ V. A = K global planes (rows, exact); B = A-planes at brow=col (exact V).
__device__ __forceinline__ void mm_p1(
    const unsigned short* __restrict__ kh, const unsigned short* __restrict__ km,
    const unsigned short* __restrict__ kl,
    const char* Ah, const char* Am, const char* Al,
    int R0, int C0, int l16, int lg, f32x4 acc[2][4]) {
  #pragma unroll 1
  for (int kc = 0; kc < Fc; kc += 32) {
    int ko = kc + lg*8;
    bf16x8 ah[2], am[2], al[2], bh[4], bm[4], bl[4];
    #pragma unroll
    for (int m = 0; m < 2; ++m) {
      size_t p = (size_t)(R0+16*m+l16)*Fc + ko;
      ah[m] = *(const bf16x8*)(kh + p);
      am[m] = *(const bf16x8*)(km + p);
      al[m] = *(const bf16x8*)(kl + p);
    }
    #pragma unroll
    for (int n = 0; n < 4; ++n)
      ld3(Ah, Am, Al, C0+16*n+l16, ko, bh[n], bm[n], bl[n]);
    mm6(ah, am, al, bh, bm, bl, acc);
  }
}

// P2-P4: A = A-planes at rows (symmetric read); B = Zh/Zm LDS + Zl global (exact Z).
__device__ __forceinline__ void mm_p234(
    const char* Ah, const char* Am, const char* Al,
    const char* Zh, const char* Zm, const unsigned short* __restrict__ ZlG,
    int R0, int C0, int l16, int lg, f32x4 acc[2][4]) {
  #pragma unroll 1
  for (int kc = 0; kc < Fc; kc += 32) {
    int ko = kc + lg*8;
    bf16x8 ah[2], am[2], al[2], bh[4], bm[4], bl[4];
    #pragma unroll
    for (int m = 0; m < 2; ++m)
      ld3(Ah, Am, Al, R0+16*m+l16, ko, ah[m], am[m], al[m]);
    #pragma unroll
    for (int n = 0; n < 4; ++n) {
      int col = C0+16*n+l16;
      unsigned off = boff(col, ko);
      bh[n] = *(const bf16x8*)(Zh + off);
      bm[n] = *(const bf16x8*)(Zm + off);
      bl[n] = *(const bf16x8*)(ZlG + col*Fc + ko);
    }
    mm6(ah, am, al, bh, bm, bl, acc);
  }
}

__device__ __forceinline__ void split4(f32x4 v, u16x4& hv, u16x4& mv, u16x4& lv) {
  #pragma unroll
  for (int r = 0; r < 4; ++r) {
    unsigned short hb = f2bf_rne(v[r]); float r1 = v[r] - bf2f(hb);
    unsigned short mb = f2bf_rne(r1);   float r2 = r1 - bf2f(mb);
    hv[r] = hb; mv[r] = mb; lv[r] = f2bf_rne(r2);
  }
}
__device__ __forceinline__ void wbA3(char* Ah, char* Am, char* Al,
                                     int col, int row0, f32x4 v) {
  u16x4 hv, mv, lv;
  split4(v, hv, mv, lv);
  unsigned off = boff(col, row0);
  *(u16x4*)(Ah + off) = hv;
  *(u16x4*)(Am + off) = mv;
  *(u16x4*)(Al + off) = lv;
}
__device__ __forceinline__ void wbZ3(char* Zh, char* Zm, unsigned short* __restrict__ ZlG,
                                     int col, int row0, f32x4 v) {
  u16x4 hv, mv, lv;
  split4(v, hv, mv, lv);
  unsigned off = boff(col, row0);
  *(u16x4*)(Zh + off) = hv;
  *(u16x4*)(Zm + off) = mv;
  *(u16x4*)(ZlG + col*Fc + row0) = lv;
}

__global__ __launch_bounds__(512) void newton_ctx_kernel(
    const float* __restrict__ STASn,
    const unsigned short* __restrict__ KhG, const unsigned short* __restrict__ KmG,
    const unsigned short* __restrict__ KlG,
    const float* __restrict__ gmaxf, float* __restrict__ Vout,
    const float* __restrict__ ASg, const float* __restrict__ vg,
    const float* __restrict__ maskg, float* __restrict__ Gpart,
    unsigned short* __restrict__ ZlScr) {
  extern __shared__ char smc[];
  int tid  = threadIdx.x;

  if (blockIdx.x < BHc) {
    // ================= Newton path =================
    char* Ah = smc;
    char* Am = smc + 32768;
    char* Al = smc + 65536;
    char* Zh = smc + 98304;
    char* Zm = smc + 131072;
    int bh = blockIdx.x;
    const float* Kp = STASn + (size_t)bh*Fc*Fc;
    const unsigned short* kh = KhG + (size_t)bh*Fc*Fc;
    const unsigned short* km = KmG + (size_t)bh*Fc*Fc;
    const unsigned short* kl = KlG + (size_t)bh*Fc*Fc;
    unsigned short* ZlG = ZlScr + (size_t)bh*Fc*Fc;
    float ginv = 1.0f / gmaxf[0];
    int lane = tid & 63;
    int wid  = tid >> 6;
    int wr = wid >> 1, wc = wid & 1;
    int l16 = lane & 15, lg = lane >> 4;
    int R0 = wr*32, C0 = wc*64;
    int drow0 = lg*4;

    f32x4 vreg[2][4];
    #pragma unroll
    for (int m = 0; m < 2; ++m)
      #pragma unroll
      for (int n = 0; n < 4; ++n) {
        int col = C0 + 16*n + l16;
        #pragma unroll
        for (int r = 0; r < 4; ++r)
          vreg[m][n][r] = Kp[(size_t)(R0 + 16*m + drow0 + r)*Fc + col] * ginv;
        wbA3(Ah, Am, Al, col, R0 + 16*m + drow0, vreg[m][n]);
      }
    __syncthreads();

    f32x4 fin[2][4];
    for (int it = 0; it < 6; ++it) {
      f32x4 acc[2][4];
      // P1: Z = K @ V
      #pragma unroll
      for (int m = 0; m < 2; ++m) for (int n = 0; n < 4; ++n) acc[m][n] = 0.f;
      mm_p1(kh, km, kl, Ah, Am, Al, R0, C0, l16, lg, acc);
      #pragma unroll
      for (int m = 0; m < 2; ++m)
        #pragma unroll
        for (int n = 0; n < 4; ++n)
          wbZ3(Zh, Zm, ZlG, C0 + 16*n + l16, R0 + 16*m + drow0, acc[m][n]);
      __syncthreads();

      // P2: W1 = V @ Z ; fin = 13V - 15W1
      #pragma unroll
      for (int m = 0; m < 2; ++m) for (int n = 0; n < 4; ++n) acc[m][n] = 0.f;
      mm_p234(Ah, Am, Al, Zh, Zm, ZlG, R0, C0, l16, lg, acc);
      #pragma unroll
      for (int m = 0; m < 2; ++m)
        #pragma unroll
        for (int n = 0; n < 4; ++n)
          fin[m][n] = 13.f*vreg[m][n] - 15.f*acc[m][n];
      __syncthreads();
      #pragma unroll
      for (int m = 0; m < 2; ++m)
        #pragma unroll
        for (int n = 0; n < 4; ++n)
          wbA3(Ah, Am, Al, C0 + 16*n + l16, R0 + 16*m + drow0, acc[m][n]);
      __syncthreads();

      // P3: W2 = W1 @ Z ; fin += 7W2
      #pragma unroll
      for (int m = 0; m < 2; ++m) for (int n = 0; n < 4; ++n) acc[m][n] = 0.f;
      mm_p234(Ah, Am, Al, Zh, Zm, ZlG, R0, C0, l16, lg, acc);
      #pragma unroll
      for (int m = 0; m < 2; ++m)
        #pragma unroll
        for (int n = 0; n < 4; ++n)
          fin[m][n] += 7.f*acc[m][n];
      __syncthreads();
      #pragma unroll
      for (int m = 0; m < 2; ++m)
        #pragma unroll
        for (int n = 0; n < 4; ++n)
          wbA3(Ah, Am, Al, C0 + 16*n + l16, R0 + 16*m + drow0, acc[m][n]);
      __syncthreads();

      // P4: W3 = W2 @ Z ; V <- 0.25(fin - W3)
      #pragma unroll
      for (int m = 0; m < 2; ++m) for (int n = 0; n < 4; ++n) acc[m][n] = 0.f;
      mm_p234(Ah, Am, Al, Zh, Zm, ZlG, R0, C0, l16, lg, acc);
      #pragma unroll
      for (int m = 0; m < 2; ++m)
        #pragma unroll
        for (int n = 0; n < 4; ++n) {
          fin[m][n] = 0.25f*(fin[m][n] - acc[m][n]);
          vreg[m][n] = fin[m][n];
        }
      __syncthreads();
      #pragma unroll
      for (int m = 0; m < 2; ++m)
        #pragma unroll
        for (int n = 0; n < 4; ++n)
          wbA3(Ah, Am, Al, C0 + 16*n + l16, R0 + 16*m + drow0, fin[m][n]);
      __syncthreads();
    }

    float* Vo = Vout + (size_t)bh*Fc*Fc;
    #pragma unroll
    for (int m = 0; m < 2; ++m)
      #pragma unroll
      for (int n = 0; n < 4; ++n) {
        int col = C0 + 16*n + l16;
        #pragma unroll
        for (int r = 0; r < 4; ++r)
          Vo[(size_t)(R0 + 16*m + drow0 + r)*Fc + col] = vreg[m][n][r];
      }
  } else {
    // ================= ctx_raw path: G_part = K^T (m^2 v) over a 512-row chunk ====
    float* Ksh = (float*)smc;              // [64][128]
    float* vsh = (float*)(smc + 32768);    // [64][64]
    int id = blockIdx.x - BHc;             // 0..127
    int cbh = id >> 2, chunk = id & 3;
    int cb = cbh >> 3;
    int t0 = chunk * 512;
    int f = tid & 127, g = tid >> 7;       // g in 0..3
    float acc[16];
    #pragma unroll
    for (int j = 0; j < 16; ++j) acc[j] = 0.f;
    for (int sub = 0; sub < 8; ++sub) {
      __syncthreads();
      int ts = t0 + sub*64;
      for (int i = tid; i < 64*32; i += 512) {
        int r = i >> 5, c4 = i & 31;
        *(float4*)&Ksh[r*128 + c4*4] =
            *(const float4*)(ASg + ((size_t)cbh*T2c + Nc + ts + r)*Fc + c4*4);
      }
      for (int i = tid; i < 64*16; i += 512) {
        int r = i >> 4, c4 = i & 15;
        float mk = maskg[cb*Nc + ts + r];
        float m2 = mk*mk;
        float4 x = *(const float4*)(vg + ((size_t)cbh*Nc + ts + r)*Dc + c4*4);
        x.x*=m2; x.y*=m2; x.z*=m2; x.w*=m2;
        *(float4*)&vsh[r*64 + c4*4] = x;
      }
      __syncthreads();
      #pragma unroll 2
      for (int tl = 0; tl < 64; ++tl) {
        float kf = Ksh[tl*128 + f];
        #pragma unroll
        for (int j4 = 0; j4 < 4; ++j4) {
          float4 vv = *(const float4*)&vsh[tl*64 + g*16 + j4*4];
          acc[j4*4+0] += kf*vv.x; acc[j4*4+1] += kf*vv.y;
          acc[j4*4+2] += kf*vv.z; acc[j4*4+3] += kf*vv.w;
        }
      }
    }
    float* gp = Gpart + ((((size_t)cbh*4 + chunk)*128 + f)*64 + g*16);
    #pragma unroll
    for (int j4 = 0; j4 < 4; ++j4)
      *(float4*)(gp + j4*4) = *(const float4*)&acc[j4*4];
  }
}

// ---------------- ctx_fix ----------------
__global__ __launch_bounds__(256) void ctx_fix_kernel(
    const float* __restrict__ Gpart, const float* __restrict__ Vinv,
    const float* __restrict__ Dinv, float* __restrict__ ctxo) {
  __shared__ float DG[128*64];
  __shared__ float Dl[128];
  int bh = blockIdx.x;
  int tid = threadIdx.x;
  if (tid < 128) Dl[tid] = Dinv[bh*Fc + tid];
  __syncthreads();
  for (int i = tid; i < 2048; i += 256) {
    int e = i >> 4, c4 = i & 15;
    const float* g0 = Gpart + ((((size_t)bh*4)*128 + e)*64 + c4*4);
    float4 s0 = *(const float4*)(g0);
    float4 s1 = *(const float4*)(g0 + 8192);
    float4 s2 = *(const float4*)(g0 + 16384);
    float4 s3 = *(const float4*)(g0 + 24576);
    float de = Dl[e];
    float4 o;
    o.x = (s0.x+s1.x+s2.x+s3.x)*de;
    o.y = (s0.y+s1.y+s2.y+s3.y)*de;
    o.z = (s0.z+s1.z+s2.z+s3.z)*de;
    o.w = (s0.w+s1.w+s2.w+s3.w)*de;
    *(float4*)&DG[e*64 + c4*4] = o;
  }
  __syncthreads();
  int f = tid & 127, half = tid >> 7;
  float acc[32];
  #pragma unroll
  for (int j = 0; j < 32; ++j) acc[j] = 0.f;
  for (int e = 0; e < 128; ++e) {
    float s = Vinv[(size_t)bh*Fc*Fc + (size_t)e*Fc + f];
    #pragma unroll
    for (int j4 = 0; j4 < 8; ++j4) {
      float4 dg = *(const float4*)&DG[e*64 + half*32 + j4*4];
      acc[j4*4+0] += s*dg.x; acc[j4*4+1] += s*dg.y;
      acc[j4*4+2] += s*dg.z; acc[j4*4+3] += s*dg.w;
    }
  }
  float df = Dl[f];
  float* op = ctxo + (size_t)bh*Fc*Dc + f*Dc + half*32;
  #pragma unroll
  for (int j4 = 0; j4 < 8; ++j4) {
    float4 o;
    o.x = acc[j4*4+0]*df; o.y = acc[j4*4+1]*df;
    o.z = acc[j4*4+2]*df; o.w = acc[j4*4+3]*df;
    *(float4*)(op + j4*4) = o;
  }
}

// ---------------- out = Q @ context ----------------
__global__ __launch_bounds__(256) void out_kernel(
    const float* __restrict__ AS, const float* __restrict__ ctx,
    float* __restrict__ out) {
  extern __shared__ float smo[];
  float* Asq = smo;            // [64][132]
  float* Cs  = smo + 64*132;   // [128][64]
  int bh = blockIdx.y;
  int row0 = blockIdx.x * 64;
  int tid = threadIdx.x;
  int tr = tid >> 4, tc = tid & 15;
  for (int i = tid; i < 64*32; i += 256) {
    int r = i >> 5, kq = i & 31;
    *(float4*)&Asq[r*132 + kq*4] =
        *(const float4*)(AS + ((size_t)bh*T2c + row0 + r)*Fc + kq*4);
  }
  for (int i = tid; i < 128*16; i += 256) {
    int r = i >> 4, kq = i & 15;
    *(float4*)&Cs[r*64 + kq*4] =
        *(const float4*)(ctx + (size_t)bh*Fc*Dc + r*Dc + kq*4);
  }
  __syncthreads();
  float acc[4][4] = {};
  #pragma unroll 2
  for (int kk = 0; kk < Fc; ++kk) {
    float4 bv = *(const float4*)&Cs[kk*64 + tc*4];
    float a0 = Asq[(tr*4+0)*132 + kk];
    float a1 = Asq[(tr*4+1)*132 + kk];
    float a2 = Asq[(tr*4+2)*132 + kk];
    float a3 = Asq[(tr*4+3)*132 + kk];
    acc[0][0] += a0*bv.x; acc[0][1] += a0*bv.y; acc[0][2] += a0*bv.z; acc[0][3] += a0*bv.w;
    acc[1][0] += a1*bv.x; acc[1][1] += a1*bv.y; acc[1][2] += a1*bv.z; acc[1][3] += a1*bv.w;
    acc[2][0] += a2*bv.x; acc[2][1] += a2*bv.y; acc[2][2] += a2*bv.z; acc[2][3] += a2*bv.w;
    acc[3][0] += a3*bv.x; acc[3][1] += a3*bv.y; acc[3][2] += a3*bv.z; acc[3][3] += a3*bv.w;
  }
  #pragma unroll
  for (int i = 0; i < 4; ++i) {
    float4 o;
    o.x = acc[i][0]; o.y = acc[i][1]; o.z = acc[i][2]; o.w = acc[i][3];
    *(float4*)(out + ((size_t)bh*Nc + row0 + tr*4 + i)*Dc + tc*4) = o;
  }
}

extern "C" void kernel_launch(void* const* d_in, const int* in_sizes, int n_in,
                              void* d_out, int out_size, void* d_ws, size_t ws_size,
                              hipStream_t stream) {
  const float* q    = (const float*)d_in[0];
  const float* k    = (const float*)d_in[1];
  const float* v    = (const float*)d_in[2];
  const float* mask = (const float*)d_in[3];
  const float* sign = (const float*)d_in[4];
  const int*   sketch = (const int*)d_in[5];
  float* out = (float*)d_out;
  float* ws  = (float*)d_ws;

  unsigned short* xsh = (unsigned short*)(ws + OFF_XSH);
  unsigned short* xsm = (unsigned short*)(ws + OFF_XSM);
  unsigned short* xsl = (unsigned short*)(ws + OFF_XSL);
  unsigned short* kh  = (unsigned short*)(ws + OFF_KH);
  unsigned short* km  = (unsigned short*)(ws + OFF_KM);
  unsigned short* kl  = (unsigned short*)(ws + OFF_KL);
  unsigned short* zsc = (unsigned short*)(ws + OFF_ZSC);

  hipMemsetAsync(ws + OFF_GMAX, 0, sizeof(float), stream);

  diag1_kernel<<<BHc*T2c*16/256, 256, 0, stream>>>(q, k, mask, ws + OFF_DIAG1);
  gather_kernel<<<BHc*Jc*16/256, 256, 0, stream>>>(q, k, mask, sketch, ws + OFF_DIAG1,
                                                   xsh, xsm, xsl, ws + OFF_DIAG2);
  as_mfma_kernel<<<dim3(T2c/64, BHc), 256, 0, stream>>>(q, k, mask, xsh, xsm, xsl,
      ws + OFF_DIAG1, ws + OFF_DIAG2, sign, ws + OFF_AS);
  stas_kernel<<<BHc, 256, 128*129*sizeof(float), stream>>>(ws + OFF_AS, sketch, sign,
      ws + OFF_STASN, ws + OFF_DINV, kh, km, kl, (unsigned int*)(ws + OFF_GMAX));
  newton_ctx_kernel<<<BHc + 128, 512, 163840, stream>>>(ws + OFF_STASN, kh, km, kl,
      ws + OFF_GMAX, ws + OFF_VBUF, ws + OFF_AS, v, mask, ws + OFF_GPART, zsc);
  ctx_fix_kernel<<<BHc, 256, 0, stream>>>(ws + OFF_GPART, ws + OFF_VBUF,
      ws + OFF_DINV, ws + OFF_CTX);
  out_kernel<<<dim3(Nc/64, BHc), 256, (64*132 + 128*64)*sizeof(float), stream>>>(
      ws + OFF_AS, ws + OFF_CTX, out);
}